// Round 1
// baseline (790.925 us; speedup 1.0000x reference)
//
#include <hip/hip_runtime.h>
#include <math.h>

// Problem constants
constexpr int Bb = 2, Ss = 2048, Dd = 1024, Hh = 16, Kk = 16;
// GEMM tiling
constexpr int BM = 128, BN = 128, BK = 16;

// ---------------------------------------------------------------------------
// Tiled f32 GEMM: C = act(A @ W + bias). A:[M,Kd] row-major, W:[Kd,N] row-major.
// blockIdx.z selects among up to 3 (W, bias, C) triples (QKV fusion).
// 256 threads, 8x8 per-thread microtile, BK=16 K-tiles staged in LDS.
// All dims divisible by tiles (M=4096, N in {512,1024}, Kd=1024).
// ---------------------------------------------------------------------------
template<int ACT>
__global__ void __launch_bounds__(256) gemm_f32(
    const float* __restrict__ A,
    const float* __restrict__ W0, const float* __restrict__ W1, const float* __restrict__ W2,
    const float* __restrict__ b0, const float* __restrict__ b1, const float* __restrict__ b2,
    float* __restrict__ C0, float* __restrict__ C1, float* __restrict__ C2,
    int M, int N, int Kd)
{
    const float* W    = (blockIdx.z == 0) ? W0 : (blockIdx.z == 1) ? W1 : W2;
    const float* bias = (blockIdx.z == 0) ? b0 : (blockIdx.z == 1) ? b1 : b2;
    float*       C    = (blockIdx.z == 0) ? C0 : (blockIdx.z == 1) ? C1 : C2;

    __shared__ float As[BK][BM + 4];   // +4 pad keeps float4 alignment, breaks bank conflicts
    __shared__ float Bs[BK][BN + 4];

    const int t  = threadIdx.x;
    const int bm = blockIdx.y * BM;
    const int bn = blockIdx.x * BN;
    const int tx = t & 15;       // col group (8 cols each)
    const int ty = t >> 4;       // row group (8 rows each)

    float acc[8][8] = {};

    for (int k0 = 0; k0 < Kd; k0 += BK) {
        // Stage A tile (BM x BK) transposed, and W tile (BK x BN), via float4.
        #pragma unroll
        for (int l = 0; l < 2; ++l) {
            int idx = t + l * 256;
            // A: 128 rows x 16 k = 512 float4
            int arow = idx >> 2;
            int akc  = (idx & 3) * 4;
            float4 av = *(const float4*)(A + (size_t)(bm + arow) * Kd + k0 + akc);
            As[akc + 0][arow] = av.x;
            As[akc + 1][arow] = av.y;
            As[akc + 2][arow] = av.z;
            As[akc + 3][arow] = av.w;
            // W: 16 k x 128 cols = 512 float4
            int wk = idx >> 5;
            int nc = (idx & 31) * 4;
            *(float4*)&Bs[wk][nc] = *(const float4*)(W + (size_t)(k0 + wk) * N + bn + nc);
        }
        __syncthreads();

        #pragma unroll
        for (int kq = 0; kq < BK; ++kq) {
            float a[8], b[8];
            *(float4*)&a[0] = *(const float4*)&As[kq][ty * 8];
            *(float4*)&a[4] = *(const float4*)&As[kq][ty * 8 + 4];
            *(float4*)&b[0] = *(const float4*)&Bs[kq][tx * 8];
            *(float4*)&b[4] = *(const float4*)&Bs[kq][tx * 8 + 4];
            #pragma unroll
            for (int i = 0; i < 8; ++i)
                #pragma unroll
                for (int j = 0; j < 8; ++j)
                    acc[i][j] = fmaf(a[i], b[j], acc[i][j]);
        }
        __syncthreads();
    }

    // Epilogue: bias (+ optional relu), float4 stores.
    #pragma unroll
    for (int i = 0; i < 8; ++i) {
        size_t row = (size_t)(bm + ty * 8 + i);
        float* crow = C + row * N + bn + tx * 8;
        const float* brow = bias + bn + tx * 8;
        #pragma unroll
        for (int j = 0; j < 8; j += 4) {
            float4 r;
            r.x = acc[i][j + 0] + brow[j + 0];
            r.y = acc[i][j + 1] + brow[j + 1];
            r.z = acc[i][j + 2] + brow[j + 2];
            r.w = acc[i][j + 3] + brow[j + 3];
            if (ACT) {
                r.x = fmaxf(r.x, 0.f); r.y = fmaxf(r.y, 0.f);
                r.z = fmaxf(r.z, 0.f); r.w = fmaxf(r.w, 0.f);
            }
            *(float4*)(crow + j) = r;
        }
    }
}

// ---------------------------------------------------------------------------
// Indexer second layer: z[row] = Hs[row,:] . Ws2 + bs2  (pre-sigmoid logit).
// Sigmoid is monotone, so top-k on z == top-k on sigmoid(z); skipping sigmoid
// removes any risk of implementation-dependent order flips.
// One wave per row, 4 rows per block.
// ---------------------------------------------------------------------------
__global__ void __launch_bounds__(256) imp_kernel(
    const float* __restrict__ Hs, const float* __restrict__ Ws2,
    const float* __restrict__ bs2, float* __restrict__ imp)
{
    int lane = threadIdx.x & 63;
    int row  = blockIdx.x * 4 + (threadIdx.x >> 6);
    const float* hr = Hs + (size_t)row * 512;
    float s = 0.f;
    for (int j = lane; j < 512; j += 64) s += hr[j] * Ws2[j];
    #pragma unroll
    for (int off = 32; off > 0; off >>= 1) s += __shfl_xor(s, off, 64);
    if (lane == 0) imp[row] = s + bs2[0];
}

// ---------------------------------------------------------------------------
// Exact top-K per batch via K iterative argmax passes (ties -> smaller index,
// matching jax.lax.top_k's stable descending order => same selected SET).
// Also zero-inits is_sel (ws is poisoned every call).
// ---------------------------------------------------------------------------
__global__ void __launch_bounds__(256) topk_kernel(
    const float* __restrict__ imp, int* __restrict__ sel_idx, int* __restrict__ is_sel)
{
    int b = blockIdx.x;
    int t = threadIdx.x;
    __shared__ float vals[Ss];
    __shared__ float sv[256];
    __shared__ int   si[256];

    for (int j = t; j < Ss; j += 256) {
        vals[j] = imp[b * Ss + j];
        is_sel[b * Ss + j] = 0;
    }
    __syncthreads();

    for (int it = 0; it < Kk; ++it) {
        float best = -1e30f; int bidx = 0x7fffffff;
        for (int j = t; j < Ss; j += 256) {
            float v = vals[j];
            if (v > best || (v == best && j < bidx)) { best = v; bidx = j; }
        }
        sv[t] = best; si[t] = bidx;
        __syncthreads();
        for (int off = 128; off > 0; off >>= 1) {
            if (t < off) {
                float ov = sv[t + off]; int oi = si[t + off];
                if (ov > sv[t] || (ov == sv[t] && oi < si[t])) { sv[t] = ov; si[t] = oi; }
            }
            __syncthreads();
        }
        if (t == 0) {
            sel_idx[b * Kk + it] = si[0];
            is_sel[b * Ss + si[0]] = 1;
            vals[si[0]] = -1e30f;
        }
        __syncthreads();
    }
}

// ---------------------------------------------------------------------------
// Sparse-row attention: for each NON-selected query row i, attend over only
// the K=16 selected keys. One wave per (b, i, h). Selected rows exit early
// (handled by attn_dense).
// ---------------------------------------------------------------------------
__global__ void __launch_bounds__(64) attn_sparse(
    const float* __restrict__ q, const float* __restrict__ k, const float* __restrict__ v,
    const int* __restrict__ sel_idx, const int* __restrict__ is_sel,
    float* __restrict__ att)
{
    int bid = blockIdx.x;
    int h   = bid & (Hh - 1);
    int bi  = bid >> 4;
    int i   = bi & (Ss - 1);
    int b   = bi >> 11;
    if (is_sel[b * Ss + i]) return;

    int lane = threadIdx.x;
    __shared__ __align__(16) float qsh[64];
    __shared__ float wsh[Kk];
    __shared__ int   sj[Kk];

    const float* qrow = q + ((size_t)(b * Ss + i)) * Dd + h * 64;
    qsh[lane] = qrow[lane];
    if (lane < Kk) sj[lane] = sel_idx[b * Kk + lane];
    __syncthreads();

    float score = -1e30f;
    if (lane < Kk) {
        const float4* k4 = (const float4*)(k + ((size_t)(b * Ss + sj[lane])) * Dd + h * 64);
        const float4* q4 = (const float4*)qsh;
        float s = 0.f;
        #pragma unroll
        for (int d4 = 0; d4 < 16; ++d4) {
            float4 kv = k4[d4];
            float4 qv = q4[d4];
            s += qv.x * kv.x + qv.y * kv.y + qv.z * kv.z + qv.w * kv.w;
        }
        score = s * 0.125f;   // 1/sqrt(64)
    }
    // softmax across lanes 0..15 (group 0 of width-16 shuffles)
    float m = score;
    #pragma unroll
    for (int off = 8; off > 0; off >>= 1) m = fmaxf(m, __shfl_xor(m, off, 16));
    float e = (lane < Kk) ? __expf(score - m) : 0.f;
    float ssum = e;
    #pragma unroll
    for (int off = 8; off > 0; off >>= 1) ssum += __shfl_xor(ssum, off, 16);
    if (lane < Kk) wsh[lane] = e / ssum;
    __syncthreads();

    float o = 0.f;
    #pragma unroll
    for (int j = 0; j < Kk; ++j) {
        const float* vrow = v + ((size_t)(b * Ss + sj[j])) * Dd + h * 64;
        o += wsh[j] * vrow[lane];
    }
    att[((size_t)(b * Ss + i)) * Dd + h * 64 + lane] = o;
}

// ---------------------------------------------------------------------------
// Dense-row attention: the K selected query rows attend over ALL S keys.
// One block (256 threads) per (b, selected-row, h). Scores staged in LDS.
// ---------------------------------------------------------------------------
__global__ void __launch_bounds__(256) attn_dense(
    const float* __restrict__ q, const float* __restrict__ k, const float* __restrict__ v,
    const int* __restrict__ sel_idx, float* __restrict__ att)
{
    int bid = blockIdx.x;
    int h   = bid & (Hh - 1);
    int r   = bid >> 4;
    int kkx = r & (Kk - 1);
    int b   = r >> 4;
    int i   = sel_idx[b * Kk + kkx];
    int t   = threadIdx.x;

    __shared__ __align__(16) float qs[64];
    __shared__ float pbuf[Ss];
    __shared__ float red[256];
    __shared__ float ored[4][64];

    const float* qrow = q + ((size_t)(b * Ss + i)) * Dd + h * 64;
    if (t < 64) qs[t] = qrow[t];
    __syncthreads();

    float lmax = -1e30f;
    const float4* q4 = (const float4*)qs;
    for (int j = t; j < Ss; j += 256) {
        const float4* k4 = (const float4*)(k + ((size_t)(b * Ss + j)) * Dd + h * 64);
        float s = 0.f;
        #pragma unroll
        for (int d4 = 0; d4 < 16; ++d4) {
            float4 kv = k4[d4];
            float4 qv = q4[d4];
            s += qv.x * kv.x + qv.y * kv.y + qv.z * kv.z + qv.w * kv.w;
        }
        s *= 0.125f;
        pbuf[j] = s;
        lmax = fmaxf(lmax, s);
    }
    red[t] = lmax;
    __syncthreads();
    for (int off = 128; off > 0; off >>= 1) {
        if (t < off) red[t] = fmaxf(red[t], red[t + off]);
        __syncthreads();
    }
    float m = red[0];
    __syncthreads();

    float lsum = 0.f;
    for (int j = t; j < Ss; j += 256) {
        float e = __expf(pbuf[j] - m);
        pbuf[j] = e;
        lsum += e;
    }
    red[t] = lsum;
    __syncthreads();
    for (int off = 128; off > 0; off >>= 1) {
        if (t < off) red[t] += red[t + off];
        __syncthreads();
    }
    float inv = 1.0f / red[0];
    __syncthreads();

    // out[d] = inv * sum_j p[j] * v[j][d]; 4 j-groups x 64 lanes
    int d = t & 63;
    int g = t >> 6;
    float o = 0.f;
    for (int j = g * (Ss / 4); j < (g + 1) * (Ss / 4); ++j) {
        o += pbuf[j] * v[((size_t)(b * Ss + j)) * Dd + h * 64 + d];
    }
    ored[g][d] = o;
    __syncthreads();
    if (t < 64) {
        float s = (ored[0][t] + ored[1][t] + ored[2][t] + ored[3][t]) * inv;
        att[((size_t)(b * Ss + i)) * Dd + h * 64 + t] = s;
    }
}

// ---------------------------------------------------------------------------
extern "C" void kernel_launch(void* const* d_in, const int* in_sizes, int n_in,
                              void* d_out, int out_size, void* d_ws, size_t ws_size,
                              hipStream_t stream)
{
    const float* x   = (const float*)d_in[0];
    const float* Wq  = (const float*)d_in[1];
    const float* bq  = (const float*)d_in[2];
    const float* Wk  = (const float*)d_in[3];
    const float* bk  = (const float*)d_in[4];
    const float* Wv  = (const float*)d_in[5];
    const float* bv  = (const float*)d_in[6];
    const float* Wo  = (const float*)d_in[7];
    const float* bo  = (const float*)d_in[8];
    const float* Ws1 = (const float*)d_in[9];
    const float* bs1 = (const float*)d_in[10];
    const float* Ws2 = (const float*)d_in[11];
    const float* bs2 = (const float*)d_in[12];
    float* out = (float*)d_out;

    const size_t MSD = (size_t)Bb * Ss * Dd;   // 4,194,304 elems
    char* p = (char*)d_ws;
    float* q   = (float*)p; p += MSD * sizeof(float);
    float* kx  = (float*)p; p += MSD * sizeof(float);
    float* vx  = (float*)p; p += MSD * sizeof(float);
    float* att = (float*)p; p += MSD * sizeof(float);
    float* imp = (float*)p; p += (size_t)Bb * Ss * sizeof(float);
    int* sel_idx = (int*)p; p += (size_t)Bb * Kk * sizeof(int);
    int* is_sel  = (int*)p; p += (size_t)Bb * Ss * sizeof(int);
    float* Hs = att;   // reuse: Hs (8 MB) consumed by imp_kernel before att is written

    const int M = Bb * Ss;   // 4096

    // 1) Indexer hidden: Hs = relu(x @ Ws1 + bs1)   [4096 x 512]
    gemm_f32<1><<<dim3(512 / BN, M / BM, 1), 256, 0, stream>>>(
        x, Ws1, Ws1, Ws1, bs1, bs1, bs1, Hs, Hs, Hs, M, 512, Dd);
    // 2) Indexer logit z = Hs @ Ws2 + bs2 (pre-sigmoid; monotone => same top-k)
    imp_kernel<<<dim3(M / 4), 256, 0, stream>>>(Hs, Ws2, bs2, imp);
    // 3) Exact top-K per batch
    topk_kernel<<<dim3(Bb), 256, 0, stream>>>(imp, sel_idx, is_sel);
    // 4) QKV projections (fused via gridDim.z)
    gemm_f32<0><<<dim3(Dd / BN, M / BM, 3), 256, 0, stream>>>(
        x, Wq, Wk, Wv, bq, bk, bv, q, kx, vx, M, Dd, Dd);
    // 5) Non-selected rows: attend over 16 selected keys only
    attn_sparse<<<dim3(Bb * Ss * Hh), 64, 0, stream>>>(q, kx, vx, sel_idx, is_sel, att);
    // 6) Selected rows: full attention over all 2048 keys
    attn_dense<<<dim3(Bb * Kk * Hh), 256, 0, stream>>>(q, kx, vx, sel_idx, att);
    // 7) Output projection
    gemm_f32<0><<<dim3(Dd / BN, M / BM, 1), 256, 0, stream>>>(
        att, Wo, Wo, Wo, bo, bo, bo, out, out, out, M, Dd, Dd);
}

// Round 2
// 384.906 us; speedup vs baseline: 2.0549x; 2.0549x over previous
//
#include <hip/hip_runtime.h>
#include <math.h>

// Problem constants
constexpr int Bb = 2, Ss = 2048, Dd = 1024, Hh = 16, Kk = 16;
// f32 GEMM tiling (indexer only)
constexpr int BM = 128, BN = 128, BK = 16;

typedef __bf16 bf16x8 __attribute__((ext_vector_type(8)));
typedef __bf16 bf16x4 __attribute__((ext_vector_type(4)));
typedef float  f32x4  __attribute__((ext_vector_type(4)));

__device__ __forceinline__ void gld_lds16(const void* g, void* l) {
    __builtin_amdgcn_global_load_lds(
        (const __attribute__((address_space(1))) unsigned int*)g,
        (__attribute__((address_space(3))) unsigned int*)l, 16, 0, 0);
}

// ---------------------------------------------------------------------------
// bf16 MFMA GEMM (m97 structure): C = A @ BT^T + bias, f32 out.
// A:[M,K] bf16 row-major. BT:[N,K] bf16 row-major (pre-transposed weights).
// 128x128 tile, BK=32, 4 waves, each wave a 64x64 quadrant via 4x4 of
// 16x16x32 MFMA. Staging via global_load_lds width=16 (lane-linear LDS).
// blockIdx.z selects among up to 3 (BT, bias, C) triples (QKV fusion).
// ---------------------------------------------------------------------------
__global__ void __launch_bounds__(256) gemm_bf16(
    const __bf16* __restrict__ A,
    const __bf16* __restrict__ BT0, const __bf16* __restrict__ BT1, const __bf16* __restrict__ BT2,
    const float* __restrict__ b0, const float* __restrict__ b1, const float* __restrict__ b2,
    float* __restrict__ C0, float* __restrict__ C1, float* __restrict__ C2,
    int M, int N, int K)
{
    const __bf16* BT  = (blockIdx.z == 0) ? BT0 : (blockIdx.z == 1) ? BT1 : BT2;
    const float* bias = (blockIdx.z == 0) ? b0  : (blockIdx.z == 1) ? b1  : b2;
    float*       C    = (blockIdx.z == 0) ? C0  : (blockIdx.z == 1) ? C1  : C2;

    __shared__ __bf16 As[128 * 32];   // lane-linear: chunk c -> bytes [16c,16c+16)
    __shared__ __bf16 Bs[128 * 32];   // == row-major [128][32], no padding

    const int t    = threadIdx.x;
    const int wave = t >> 6;
    const int lane = t & 63;
    const int bm   = blockIdx.y * 128;
    const int bn   = blockIdx.x * 128;
    const int wm   = (wave & 1) * 64;
    const int wn   = (wave >> 1) * 64;
    const int fr   = lane & 15;        // fragment row (m / n)
    const int fq   = lane >> 4;        // quad -> k offset fq*8

    f32x4 acc[4][4] = {};

    for (int k0 = 0; k0 < K; k0 += 32) {
        // Stage A tile (128 rows x 32 k) and BT tile, 16 B per lane.
        #pragma unroll
        for (int l = 0; l < 2; ++l) {
            int c = l * 256 + t;                       // chunk 0..511
            const __bf16* ga = A + (size_t)(bm + (c >> 2)) * K + k0 + (c & 3) * 8;
            gld_lds16(ga, As + (size_t)(l * 256 + wave * 64) * 8);
            const __bf16* gb = BT + (size_t)(bn + (c >> 2)) * K + k0 + (c & 3) * 8;
            gld_lds16(gb, Bs + (size_t)(l * 256 + wave * 64) * 8);
        }
        __syncthreads();

        bf16x8 af[4], bf[4];
        #pragma unroll
        for (int i = 0; i < 4; ++i)
            af[i] = *(const bf16x8*)(As + (wm + i * 16 + fr) * 32 + fq * 8);
        #pragma unroll
        for (int j = 0; j < 4; ++j)
            bf[j] = *(const bf16x8*)(Bs + (wn + j * 16 + fr) * 32 + fq * 8);
        #pragma unroll
        for (int i = 0; i < 4; ++i)
            #pragma unroll
            for (int j = 0; j < 4; ++j)
                acc[i][j] = __builtin_amdgcn_mfma_f32_16x16x32_bf16(af[i], bf[j], acc[i][j], 0, 0, 0);
        __syncthreads();
    }

    // Epilogue. C/D layout: col = lane&15, row = (lane>>4)*4 + reg.
    const int cr = (lane >> 4) * 4;
    const int cc = lane & 15;
    #pragma unroll
    for (int j = 0; j < 4; ++j) {
        int col = bn + wn + j * 16 + cc;
        float bb = bias[col];
        #pragma unroll
        for (int i = 0; i < 4; ++i) {
            #pragma unroll
            for (int r = 0; r < 4; ++r)
                C[(size_t)(bm + wm + i * 16 + cr + r) * N + col] = acc[i][j][r] + bb;
        }
    }
}

// ---------------------------------------------------------------------------
// Pack x (f32 -> bf16), float4-vectorized. Exact-size grid.
// ---------------------------------------------------------------------------
__global__ void __launch_bounds__(256) pack_x(
    const float* __restrict__ src, __bf16* __restrict__ dst)
{
    int i = blockIdx.x * 256 + threadIdx.x;
    float4 v = ((const float4*)src)[i];
    bf16x4 o = { (__bf16)v.x, (__bf16)v.y, (__bf16)v.z, (__bf16)v.w };
    ((bf16x4*)dst)[i] = o;
}

// ---------------------------------------------------------------------------
// Transpose + pack weights: WT[n][k] = bf16(W[k][n]), 1024x1024, z = which W.
// ---------------------------------------------------------------------------
__global__ void __launch_bounds__(256) transpose_pack(
    const float* __restrict__ W0, const float* __restrict__ W1,
    const float* __restrict__ W2, const float* __restrict__ W3,
    __bf16* __restrict__ T0, __bf16* __restrict__ T1,
    __bf16* __restrict__ T2, __bf16* __restrict__ T3)
{
    const float* W = (blockIdx.z == 0) ? W0 : (blockIdx.z == 1) ? W1 : (blockIdx.z == 2) ? W2 : W3;
    __bf16*      T = (blockIdx.z == 0) ? T0 : (blockIdx.z == 1) ? T1 : (blockIdx.z == 2) ? T2 : T3;

    __shared__ float tile[32][33];
    int tx = threadIdx.x & 31, ty = threadIdx.x >> 5;   // 32 x 8
    int n0 = blockIdx.x * 32, k0 = blockIdx.y * 32;
    #pragma unroll
    for (int i = 0; i < 32; i += 8)
        tile[ty + i][tx] = W[(size_t)(k0 + ty + i) * 1024 + n0 + tx];
    __syncthreads();
    #pragma unroll
    for (int i = 0; i < 32; i += 8)
        T[(size_t)(n0 + ty + i) * 1024 + k0 + tx] = (__bf16)tile[tx][ty + i];
}

// ---------------------------------------------------------------------------
// Indexer GEMM, f32, split-K x2 (exactness of top-k requires f32 here).
// P[z][M][512] = x[:, z*512:(z+1)*512] @ Ws1[z*512:(z+1)*512, :]. No bias/act
// (applied in imp_kernel after summing partials).
// ---------------------------------------------------------------------------
__global__ void __launch_bounds__(256) gemm_f32_ind(
    const float* __restrict__ A, const float* __restrict__ W,
    float* __restrict__ P, int M, int N, int Kd)
{
    float* Pz = P + (size_t)blockIdx.z * M * N;
    const int kbeg = blockIdx.z * (Kd / 2);
    const int kend = kbeg + Kd / 2;

    __shared__ float As[BK][BM + 4];
    __shared__ float Bs[BK][BN + 4];

    const int t  = threadIdx.x;
    const int bm = blockIdx.y * BM;
    const int bn = blockIdx.x * BN;
    const int tx = t & 15;
    const int ty = t >> 4;

    float acc[8][8] = {};

    for (int k0 = kbeg; k0 < kend; k0 += BK) {
        #pragma unroll
        for (int l = 0; l < 2; ++l) {
            int idx = t + l * 256;
            int arow = idx >> 2;
            int akc  = (idx & 3) * 4;
            float4 av = *(const float4*)(A + (size_t)(bm + arow) * Kd + k0 + akc);
            As[akc + 0][arow] = av.x;
            As[akc + 1][arow] = av.y;
            As[akc + 2][arow] = av.z;
            As[akc + 3][arow] = av.w;
            int wk = idx >> 5;
            int nc = (idx & 31) * 4;
            *(float4*)&Bs[wk][nc] = *(const float4*)(W + (size_t)(k0 + wk) * N + bn + nc);
        }
        __syncthreads();

        #pragma unroll
        for (int kq = 0; kq < BK; ++kq) {
            float a[8], b[8];
            *(float4*)&a[0] = *(const float4*)&As[kq][ty * 8];
            *(float4*)&a[4] = *(const float4*)&As[kq][ty * 8 + 4];
            *(float4*)&b[0] = *(const float4*)&Bs[kq][tx * 8];
            *(float4*)&b[4] = *(const float4*)&Bs[kq][tx * 8 + 4];
            #pragma unroll
            for (int i = 0; i < 8; ++i)
                #pragma unroll
                for (int j = 0; j < 8; ++j)
                    acc[i][j] = fmaf(a[i], b[j], acc[i][j]);
        }
        __syncthreads();
    }

    #pragma unroll
    for (int i = 0; i < 8; ++i) {
        float* crow = Pz + (size_t)(bm + ty * 8 + i) * N + bn + tx * 8;
        #pragma unroll
        for (int j = 0; j < 8; j += 4)
            *(float4*)(crow + j) = *(const float4*)&acc[i][j];
    }
}

// ---------------------------------------------------------------------------
// Indexer logit: z[row] = sum_j relu(P0[row,j]+P1[row,j]+bs1[j]) * Ws2[j]
// (+ bs2; pre-sigmoid — sigmoid is monotone so top-k set is identical).
// One wave per row.
// ---------------------------------------------------------------------------
__global__ void __launch_bounds__(256) imp_kernel(
    const float* __restrict__ P, const float* __restrict__ bs1,
    const float* __restrict__ Ws2, const float* __restrict__ bs2,
    float* __restrict__ imp, int M)
{
    int lane = threadIdx.x & 63;
    int row  = blockIdx.x * 4 + (threadIdx.x >> 6);
    const float* p0 = P + (size_t)row * 512;
    const float* p1 = P + (size_t)M * 512 + (size_t)row * 512;
    float s = 0.f;
    for (int j = lane; j < 512; j += 64)
        s += fmaxf(p0[j] + p1[j] + bs1[j], 0.f) * Ws2[j];
    #pragma unroll
    for (int off = 32; off > 0; off >>= 1) s += __shfl_xor(s, off, 64);
    if (lane == 0) imp[row] = s + bs2[0];
}

// ---------------------------------------------------------------------------
// Exact top-K per batch via K iterative argmax passes. Zero-inits is_sel.
// ---------------------------------------------------------------------------
__global__ void __launch_bounds__(256) topk_kernel(
    const float* __restrict__ imp, int* __restrict__ sel_idx, int* __restrict__ is_sel)
{
    int b = blockIdx.x;
    int t = threadIdx.x;
    __shared__ float vals[Ss];
    __shared__ float sv[256];
    __shared__ int   si[256];

    for (int j = t; j < Ss; j += 256) {
        vals[j] = imp[b * Ss + j];
        is_sel[b * Ss + j] = 0;
    }
    __syncthreads();

    for (int it = 0; it < Kk; ++it) {
        float best = -1e30f; int bidx = 0x7fffffff;
        for (int j = t; j < Ss; j += 256) {
            float v = vals[j];
            if (v > best || (v == best && j < bidx)) { best = v; bidx = j; }
        }
        sv[t] = best; si[t] = bidx;
        __syncthreads();
        for (int off = 128; off > 0; off >>= 1) {
            if (t < off) {
                float ov = sv[t + off]; int oi = si[t + off];
                if (ov > sv[t] || (ov == sv[t] && oi < si[t])) { sv[t] = ov; si[t] = oi; }
            }
            __syncthreads();
        }
        if (t == 0) {
            sel_idx[b * Kk + it] = si[0];
            is_sel[b * Ss + si[0]] = 1;
            vals[si[0]] = -1e30f;
        }
        __syncthreads();
    }
}

// ---------------------------------------------------------------------------
// Sparse-row attention: non-selected query rows attend over the K=16
// selected keys. One wave per (b, i, h). Writes bf16.
// ---------------------------------------------------------------------------
__global__ void __launch_bounds__(64) attn_sparse(
    const float* __restrict__ q, const float* __restrict__ k, const float* __restrict__ v,
    const int* __restrict__ sel_idx, const int* __restrict__ is_sel,
    __bf16* __restrict__ att)
{
    int bid = blockIdx.x;
    int h   = bid & (Hh - 1);
    int bi  = bid >> 4;
    int i   = bi & (Ss - 1);
    int b   = bi >> 11;
    if (is_sel[b * Ss + i]) return;

    int lane = threadIdx.x;
    __shared__ __align__(16) float qsh[64];
    __shared__ float wsh[Kk];
    __shared__ int   sj[Kk];

    const float* qrow = q + ((size_t)(b * Ss + i)) * Dd + h * 64;
    qsh[lane] = qrow[lane];
    if (lane < Kk) sj[lane] = sel_idx[b * Kk + lane];
    __syncthreads();

    float score = -1e30f;
    if (lane < Kk) {
        const float4* k4 = (const float4*)(k + ((size_t)(b * Ss + sj[lane])) * Dd + h * 64);
        const float4* q4 = (const float4*)qsh;
        float s = 0.f;
        #pragma unroll
        for (int d4 = 0; d4 < 16; ++d4) {
            float4 kv = k4[d4];
            float4 qv = q4[d4];
            s += qv.x * kv.x + qv.y * kv.y + qv.z * kv.z + qv.w * kv.w;
        }
        score = s * 0.125f;   // 1/sqrt(64)
    }
    float m = score;
    #pragma unroll
    for (int off = 8; off > 0; off >>= 1) m = fmaxf(m, __shfl_xor(m, off, 16));
    float e = (lane < Kk) ? __expf(score - m) : 0.f;
    float ssum = e;
    #pragma unroll
    for (int off = 8; off > 0; off >>= 1) ssum += __shfl_xor(ssum, off, 16);
    if (lane < Kk) wsh[lane] = e / ssum;
    __syncthreads();

    float o = 0.f;
    #pragma unroll
    for (int j = 0; j < Kk; ++j) {
        const float* vrow = v + ((size_t)(b * Ss + sj[j])) * Dd + h * 64;
        o += wsh[j] * vrow[lane];
    }
    att[((size_t)(b * Ss + i)) * Dd + h * 64 + lane] = (__bf16)o;
}

// ---------------------------------------------------------------------------
// Dense-row attention: the K selected query rows attend over ALL S keys.
// One block per (b, selected-row, h). Writes bf16.
// ---------------------------------------------------------------------------
__global__ void __launch_bounds__(256) attn_dense(
    const float* __restrict__ q, const float* __restrict__ k, const float* __restrict__ v,
    const int* __restrict__ sel_idx, __bf16* __restrict__ att)
{
    int bid = blockIdx.x;
    int h   = bid & (Hh - 1);
    int r   = bid >> 4;
    int kkx = r & (Kk - 1);
    int b   = r >> 4;
    int i   = sel_idx[b * Kk + kkx];
    int t   = threadIdx.x;

    __shared__ __align__(16) float qs[64];
    __shared__ float pbuf[Ss];
    __shared__ float red[256];
    __shared__ float ored[4][64];

    const float* qrow = q + ((size_t)(b * Ss + i)) * Dd + h * 64;
    if (t < 64) qs[t] = qrow[t];
    __syncthreads();

    float lmax = -1e30f;
    const float4* q4 = (const float4*)qs;
    for (int j = t; j < Ss; j += 256) {
        const float4* k4 = (const float4*)(k + ((size_t)(b * Ss + j)) * Dd + h * 64);
        float s = 0.f;
        #pragma unroll
        for (int d4 = 0; d4 < 16; ++d4) {
            float4 kv = k4[d4];
            float4 qv = q4[d4];
            s += qv.x * kv.x + qv.y * kv.y + qv.z * kv.z + qv.w * kv.w;
        }
        s *= 0.125f;
        pbuf[j] = s;
        lmax = fmaxf(lmax, s);
    }
    red[t] = lmax;
    __syncthreads();
    for (int off = 128; off > 0; off >>= 1) {
        if (t < off) red[t] = fmaxf(red[t], red[t + off]);
        __syncthreads();
    }
    float m = red[0];
    __syncthreads();

    float lsum = 0.f;
    for (int j = t; j < Ss; j += 256) {
        float e = __expf(pbuf[j] - m);
        pbuf[j] = e;
        lsum += e;
    }
    red[t] = lsum;
    __syncthreads();
    for (int off = 128; off > 0; off >>= 1) {
        if (t < off) red[t] += red[t + off];
        __syncthreads();
    }
    float inv = 1.0f / red[0];
    __syncthreads();

    int d = t & 63;
    int g = t >> 6;
    float o = 0.f;
    for (int j = g * (Ss / 4); j < (g + 1) * (Ss / 4); ++j)
        o += pbuf[j] * v[((size_t)(b * Ss + j)) * Dd + h * 64 + d];
    ored[g][d] = o;
    __syncthreads();
    if (t < 64) {
        float s = (ored[0][t] + ored[1][t] + ored[2][t] + ored[3][t]) * inv;
        att[((size_t)(b * Ss + i)) * Dd + h * 64 + t] = (__bf16)s;
    }
}

// ---------------------------------------------------------------------------
extern "C" void kernel_launch(void* const* d_in, const int* in_sizes, int n_in,
                              void* d_out, int out_size, void* d_ws, size_t ws_size,
                              hipStream_t stream)
{
    const float* x   = (const float*)d_in[0];
    const float* Wq  = (const float*)d_in[1];
    const float* bq  = (const float*)d_in[2];
    const float* Wk  = (const float*)d_in[3];
    const float* bk  = (const float*)d_in[4];
    const float* Wv  = (const float*)d_in[5];
    const float* bv  = (const float*)d_in[6];
    const float* Wo  = (const float*)d_in[7];
    const float* bo  = (const float*)d_in[8];
    const float* Ws1 = (const float*)d_in[9];
    const float* bs1 = (const float*)d_in[10];
    const float* Ws2 = (const float*)d_in[11];
    const float* bs2 = (const float*)d_in[12];
    float* out = (float*)d_out;

    const size_t MSD = (size_t)Bb * Ss * Dd;   // 4,194,304
    const int M = Bb * Ss;                     // 4096

    char* p = (char*)d_ws;
    float* q    = (float*)p; p += MSD * sizeof(float);
    float* kx   = (float*)p; p += MSD * sizeof(float);
    float* vx   = (float*)p; p += MSD * sizeof(float);
    float* P    = (float*)p; p += 2 * (size_t)M * 512 * sizeof(float);  // split-K partials
    __bf16* xb  = (__bf16*)p; p += MSD * sizeof(__bf16);
    __bf16* WqT = (__bf16*)p; p += (size_t)Dd * Dd * sizeof(__bf16);
    __bf16* WkT = (__bf16*)p; p += (size_t)Dd * Dd * sizeof(__bf16);
    __bf16* WvT = (__bf16*)p; p += (size_t)Dd * Dd * sizeof(__bf16);
    __bf16* WoT = (__bf16*)p; p += (size_t)Dd * Dd * sizeof(__bf16);
    float* imp  = (float*)p; p += (size_t)Bb * Ss * sizeof(float);
    int* sel_idx = (int*)p; p += (size_t)Bb * Kk * sizeof(int);
    int* is_sel  = (int*)p; p += (size_t)Bb * Ss * sizeof(int);
    __bf16* att_bf = (__bf16*)P;   // alias: P dead after imp_kernel; att written later

    // 1) Pack inputs to bf16 / transposed-bf16 weights.
    pack_x<<<dim3((int)(MSD / 4 / 256)), 256, 0, stream>>>(x, xb);
    transpose_pack<<<dim3(32, 32, 4), 256, 0, stream>>>(Wq, Wk, Wv, Wo, WqT, WkT, WvT, WoT);
    // 2) Indexer (kept f32 for exact top-k), split-K x2 for occupancy.
    gemm_f32_ind<<<dim3(512 / BN, M / BM, 2), 256, 0, stream>>>(x, Ws1, P, M, 512, Dd);
    imp_kernel<<<dim3(M / 4), 256, 0, stream>>>(P, bs1, Ws2, bs2, imp, M);
    topk_kernel<<<dim3(Bb), 256, 0, stream>>>(imp, sel_idx, is_sel);
    // 3) QKV projections, bf16 MFMA, z-fused.
    gemm_bf16<<<dim3(8, 32, 3), 256, 0, stream>>>(
        xb, WqT, WkT, WvT, bq, bk, bv, q, kx, vx, M, Dd, Dd);
    // 4) Attention (f32 in, bf16 out).
    attn_sparse<<<dim3(Bb * Ss * Hh), 64, 0, stream>>>(q, kx, vx, sel_idx, is_sel, att_bf);
    attn_dense<<<dim3(Bb * Kk * Hh), 256, 0, stream>>>(q, kx, vx, sel_idx, att_bf);
    // 5) Output projection, bf16 MFMA.
    gemm_bf16<<<dim3(8, 32, 1), 256, 0, stream>>>(
        att_bf, WoT, WoT, WoT, bo, bo, bo, out, out, out, M, Dd, Dd);
}

// Round 3
// 362.184 us; speedup vs baseline: 2.1838x; 1.0627x over previous
//
#include <hip/hip_runtime.h>
#include <math.h>

// Problem constants
constexpr int Bb = 2, Ss = 2048, Dd = 1024, Hh = 16, Kk = 16;

typedef __bf16 bf16x8 __attribute__((ext_vector_type(8)));
typedef __bf16 bf16x4 __attribute__((ext_vector_type(4)));
typedef float  f32x4  __attribute__((ext_vector_type(4)));

__device__ __forceinline__ void gld_lds16(const void* g, void* l) {
    __builtin_amdgcn_global_load_lds(
        (const __attribute__((address_space(1))) unsigned int*)g,
        (__attribute__((address_space(3))) unsigned int*)l, 16, 0, 0);
}

// ---------------------------------------------------------------------------
// bf16 MFMA GEMM (m97 structure): C = A @ BT^T + bias, f32 out.
// A:[M,K] bf16 row-major. BT:[N,K] bf16 row-major (pre-transposed weights).
// 128x128 tile, BK=32, 4 waves, each wave a 64x64 quadrant via 4x4 of
// 16x16x32 MFMA. Staging via global_load_lds width=16 (lane-linear LDS).
// blockIdx.z selects among up to 3 (BT, bias, C) triples (QKV fusion).
// ---------------------------------------------------------------------------
__global__ void __launch_bounds__(256) gemm_bf16(
    const __bf16* __restrict__ A,
    const __bf16* __restrict__ BT0, const __bf16* __restrict__ BT1, const __bf16* __restrict__ BT2,
    const float* __restrict__ b0, const float* __restrict__ b1, const float* __restrict__ b2,
    float* __restrict__ C0, float* __restrict__ C1, float* __restrict__ C2,
    int M, int N, int K)
{
    const __bf16* BT  = (blockIdx.z == 0) ? BT0 : (blockIdx.z == 1) ? BT1 : BT2;
    const float* bias = (blockIdx.z == 0) ? b0  : (blockIdx.z == 1) ? b1  : b2;
    float*       C    = (blockIdx.z == 0) ? C0  : (blockIdx.z == 1) ? C1  : C2;

    __shared__ __bf16 As[128 * 32];   // lane-linear: chunk c -> bytes [16c,16c+16)
    __shared__ __bf16 Bs[128 * 32];

    const int t    = threadIdx.x;
    const int wave = t >> 6;
    const int lane = t & 63;
    const int bm   = blockIdx.y * 128;
    const int bn   = blockIdx.x * 128;
    const int wm   = (wave & 1) * 64;
    const int wn   = (wave >> 1) * 64;
    const int fr   = lane & 15;        // fragment row (m / n)
    const int fq   = lane >> 4;        // quad -> k offset fq*8

    f32x4 acc[4][4] = {};

    for (int k0 = 0; k0 < K; k0 += 32) {
        #pragma unroll
        for (int l = 0; l < 2; ++l) {
            int c = l * 256 + t;                       // chunk 0..511
            const __bf16* ga = A + (size_t)(bm + (c >> 2)) * K + k0 + (c & 3) * 8;
            gld_lds16(ga, As + (size_t)(l * 256 + wave * 64) * 8);
            const __bf16* gb = BT + (size_t)(bn + (c >> 2)) * K + k0 + (c & 3) * 8;
            gld_lds16(gb, Bs + (size_t)(l * 256 + wave * 64) * 8);
        }
        __syncthreads();

        bf16x8 af[4], bf[4];
        #pragma unroll
        for (int i = 0; i < 4; ++i)
            af[i] = *(const bf16x8*)(As + (wm + i * 16 + fr) * 32 + fq * 8);
        #pragma unroll
        for (int j = 0; j < 4; ++j)
            bf[j] = *(const bf16x8*)(Bs + (wn + j * 16 + fr) * 32 + fq * 8);
        #pragma unroll
        for (int i = 0; i < 4; ++i)
            #pragma unroll
            for (int j = 0; j < 4; ++j)
                acc[i][j] = __builtin_amdgcn_mfma_f32_16x16x32_bf16(af[i], bf[j], acc[i][j], 0, 0, 0);
        __syncthreads();
    }

    // Epilogue. C/D layout: col = lane&15, row = (lane>>4)*4 + reg.
    const int cr = (lane >> 4) * 4;
    const int cc = lane & 15;
    #pragma unroll
    for (int j = 0; j < 4; ++j) {
        int col = bn + wn + j * 16 + cc;
        float bb = bias[col];
        #pragma unroll
        for (int i = 0; i < 4; ++i) {
            #pragma unroll
            for (int r = 0; r < 4; ++r)
                C[(size_t)(bm + wm + i * 16 + cr + r) * N + col] = acc[i][j][r] + bb;
        }
    }
}

// ---------------------------------------------------------------------------
// Split-precision indexer GEMM on matrix cores:
//   Hs = relu( x_hi@W_hi + x_hi@W_lo + x_lo@W_hi + bs1 )   (f32 out)
// where x = x_hi + x_lo (bf16 pair, ~16 mantissa bits). Dropped lo*lo term
// ~2^-17 relative => logit error ~1e-6 vs rank-gap ~7e-3: top-k exact.
// Tile 128x64, BK=32, 4 waves each 64x32 (4x2 frags). Grid 8x32 = 256 blocks.
// ---------------------------------------------------------------------------
__global__ void __launch_bounds__(256) gemm_hilo(
    const __bf16* __restrict__ Ah_g, const __bf16* __restrict__ Al_g,
    const __bf16* __restrict__ Bh_g, const __bf16* __restrict__ Bl_g,
    const float* __restrict__ bias, float* __restrict__ C,
    int M, int N, int K)
{
    __shared__ __bf16 Ah[128 * 32];
    __shared__ __bf16 Al[128 * 32];
    __shared__ __bf16 Bh[64 * 32];
    __shared__ __bf16 Bl[64 * 32];

    const int t    = threadIdx.x;
    const int wave = t >> 6;
    const int lane = t & 63;
    const int bm   = blockIdx.y * 128;
    const int bn   = blockIdx.x * 64;
    const int wm   = (wave & 1) * 64;
    const int wn   = (wave >> 1) * 32;
    const int fr   = lane & 15;
    const int fq   = lane >> 4;

    f32x4 acc[4][2] = {};

    for (int k0 = 0; k0 < K; k0 += 32) {
        #pragma unroll
        for (int l = 0; l < 2; ++l) {
            int c = l * 256 + t;                       // A chunks 0..511
            size_t goff = (size_t)(bm + (c >> 2)) * K + k0 + (c & 3) * 8;
            gld_lds16(Ah_g + goff, Ah + (size_t)(l * 256 + wave * 64) * 8);
            gld_lds16(Al_g + goff, Al + (size_t)(l * 256 + wave * 64) * 8);
        }
        {
            int c = t;                                 // B chunks 0..255
            size_t goff = (size_t)(bn + (c >> 2)) * K + k0 + (c & 3) * 8;
            gld_lds16(Bh_g + goff, Bh + (size_t)(wave * 64) * 8);
            gld_lds16(Bl_g + goff, Bl + (size_t)(wave * 64) * 8);
        }
        __syncthreads();

        bf16x8 ah[4], al[4], bh[2], bl[2];
        #pragma unroll
        for (int i = 0; i < 4; ++i) {
            ah[i] = *(const bf16x8*)(Ah + (wm + i * 16 + fr) * 32 + fq * 8);
            al[i] = *(const bf16x8*)(Al + (wm + i * 16 + fr) * 32 + fq * 8);
        }
        #pragma unroll
        for (int j = 0; j < 2; ++j) {
            bh[j] = *(const bf16x8*)(Bh + (wn + j * 16 + fr) * 32 + fq * 8);
            bl[j] = *(const bf16x8*)(Bl + (wn + j * 16 + fr) * 32 + fq * 8);
        }
        #pragma unroll
        for (int i = 0; i < 4; ++i)
            #pragma unroll
            for (int j = 0; j < 2; ++j) {
                acc[i][j] = __builtin_amdgcn_mfma_f32_16x16x32_bf16(al[i], bh[j], acc[i][j], 0, 0, 0);
                acc[i][j] = __builtin_amdgcn_mfma_f32_16x16x32_bf16(ah[i], bl[j], acc[i][j], 0, 0, 0);
                acc[i][j] = __builtin_amdgcn_mfma_f32_16x16x32_bf16(ah[i], bh[j], acc[i][j], 0, 0, 0);
            }
        __syncthreads();
    }

    const int cr = (lane >> 4) * 4;
    const int cc = lane & 15;
    #pragma unroll
    for (int j = 0; j < 2; ++j) {
        int col = bn + wn + j * 16 + cc;
        float bb = bias[col];
        #pragma unroll
        for (int i = 0; i < 4; ++i) {
            #pragma unroll
            for (int r = 0; r < 4; ++r)
                C[(size_t)(bm + wm + i * 16 + cr + r) * N + col] =
                    fmaxf(acc[i][j][r] + bb, 0.f);
        }
    }
}

// ---------------------------------------------------------------------------
// Pack x (f32 -> bf16 hi + lo residual), float4-vectorized.
// ---------------------------------------------------------------------------
__global__ void __launch_bounds__(256) pack_x_hilo(
    const float* __restrict__ src, __bf16* __restrict__ hi, __bf16* __restrict__ lo)
{
    int i = blockIdx.x * 256 + threadIdx.x;
    float4 v = ((const float4*)src)[i];
    bf16x4 h = { (__bf16)v.x, (__bf16)v.y, (__bf16)v.z, (__bf16)v.w };
    bf16x4 l = { (__bf16)(v.x - (float)h[0]), (__bf16)(v.y - (float)h[1]),
                 (__bf16)(v.z - (float)h[2]), (__bf16)(v.w - (float)h[3]) };
    ((bf16x4*)hi)[i] = h;
    ((bf16x4*)lo)[i] = l;
}

// ---------------------------------------------------------------------------
// Transpose + pack weights: WT[n][k] = bf16(W[k][n]), 1024x1024, z = which W.
// ---------------------------------------------------------------------------
__global__ void __launch_bounds__(256) transpose_pack(
    const float* __restrict__ W0, const float* __restrict__ W1,
    const float* __restrict__ W2, const float* __restrict__ W3,
    __bf16* __restrict__ T0, __bf16* __restrict__ T1,
    __bf16* __restrict__ T2, __bf16* __restrict__ T3)
{
    const float* W = (blockIdx.z == 0) ? W0 : (blockIdx.z == 1) ? W1 : (blockIdx.z == 2) ? W2 : W3;
    __bf16*      T = (blockIdx.z == 0) ? T0 : (blockIdx.z == 1) ? T1 : (blockIdx.z == 2) ? T2 : T3;

    __shared__ float tile[32][33];
    int tx = threadIdx.x & 31, ty = threadIdx.x >> 5;   // 32 x 8
    int n0 = blockIdx.x * 32, k0 = blockIdx.y * 32;
    #pragma unroll
    for (int i = 0; i < 32; i += 8)
        tile[ty + i][tx] = W[(size_t)(k0 + ty + i) * 1024 + n0 + tx];
    __syncthreads();
    #pragma unroll
    for (int i = 0; i < 32; i += 8)
        T[(size_t)(n0 + ty + i) * 1024 + k0 + tx] = (__bf16)tile[tx][ty + i];
}

// ---------------------------------------------------------------------------
// Transpose + hi/lo pack Ws1: [1024, 512] f32 -> Th/Tl [512][1024] bf16.
// ---------------------------------------------------------------------------
__global__ void __launch_bounds__(256) transpose_pack_hilo(
    const float* __restrict__ W, __bf16* __restrict__ Th, __bf16* __restrict__ Tl)
{
    __shared__ float tile[32][33];
    int tx = threadIdx.x & 31, ty = threadIdx.x >> 5;   // 32 x 8
    int n0 = blockIdx.x * 32, k0 = blockIdx.y * 32;
    #pragma unroll
    for (int i = 0; i < 32; i += 8)
        tile[ty + i][tx] = W[(size_t)(k0 + ty + i) * 512 + n0 + tx];
    __syncthreads();
    #pragma unroll
    for (int i = 0; i < 32; i += 8) {
        float v = tile[tx][ty + i];
        __bf16 h = (__bf16)v;
        Th[(size_t)(n0 + ty + i) * 1024 + k0 + tx] = h;
        Tl[(size_t)(n0 + ty + i) * 1024 + k0 + tx] = (__bf16)(v - (float)h);
    }
}

// ---------------------------------------------------------------------------
// Indexer logit: z[row] = Hs[row,:] . Ws2 + bs2 (pre-sigmoid; monotone =>
// identical top-k set). One wave per row, 4 rows per block.
// ---------------------------------------------------------------------------
__global__ void __launch_bounds__(256) imp_kernel(
    const float* __restrict__ Hs, const float* __restrict__ Ws2,
    const float* __restrict__ bs2, float* __restrict__ imp)
{
    int lane = threadIdx.x & 63;
    int row  = blockIdx.x * 4 + (threadIdx.x >> 6);
    const float* hr = Hs + (size_t)row * 512;
    float s = 0.f;
    for (int j = lane; j < 512; j += 64) s += hr[j] * Ws2[j];
    #pragma unroll
    for (int off = 32; off > 0; off >>= 1) s += __shfl_xor(s, off, 64);
    if (lane == 0) imp[row] = s + bs2[0];
}

// ---------------------------------------------------------------------------
// Exact top-K per batch via K iterative argmax passes. Zero-inits is_sel.
// ---------------------------------------------------------------------------
__global__ void __launch_bounds__(256) topk_kernel(
    const float* __restrict__ imp, int* __restrict__ sel_idx, int* __restrict__ is_sel)
{
    int b = blockIdx.x;
    int t = threadIdx.x;
    __shared__ float vals[Ss];
    __shared__ float sv[256];
    __shared__ int   si[256];

    for (int j = t; j < Ss; j += 256) {
        vals[j] = imp[b * Ss + j];
        is_sel[b * Ss + j] = 0;
    }
    __syncthreads();

    for (int it = 0; it < Kk; ++it) {
        float best = -1e30f; int bidx = 0x7fffffff;
        for (int j = t; j < Ss; j += 256) {
            float v = vals[j];
            if (v > best || (v == best && j < bidx)) { best = v; bidx = j; }
        }
        sv[t] = best; si[t] = bidx;
        __syncthreads();
        for (int off = 128; off > 0; off >>= 1) {
            if (t < off) {
                float ov = sv[t + off]; int oi = si[t + off];
                if (ov > sv[t] || (ov == sv[t] && oi < si[t])) { sv[t] = ov; si[t] = oi; }
            }
            __syncthreads();
        }
        if (t == 0) {
            sel_idx[b * Kk + it] = si[0];
            is_sel[b * Ss + si[0]] = 1;
            vals[si[0]] = -1e30f;
        }
        __syncthreads();
    }
}

// ---------------------------------------------------------------------------
// Sparse-row attention: non-selected query rows attend over the K=16
// selected keys. One wave per (b, i, h). Writes bf16.
// ---------------------------------------------------------------------------
__global__ void __launch_bounds__(64) attn_sparse(
    const float* __restrict__ q, const float* __restrict__ k, const float* __restrict__ v,
    const int* __restrict__ sel_idx, const int* __restrict__ is_sel,
    __bf16* __restrict__ att)
{
    int bid = blockIdx.x;
    int h   = bid & (Hh - 1);
    int bi  = bid >> 4;
    int i   = bi & (Ss - 1);
    int b   = bi >> 11;
    if (is_sel[b * Ss + i]) return;

    int lane = threadIdx.x;
    __shared__ __align__(16) float qsh[64];
    __shared__ float wsh[Kk];
    __shared__ int   sj[Kk];

    const float* qrow = q + ((size_t)(b * Ss + i)) * Dd + h * 64;
    qsh[lane] = qrow[lane];
    if (lane < Kk) sj[lane] = sel_idx[b * Kk + lane];
    __syncthreads();

    float score = -1e30f;
    if (lane < Kk) {
        const float4* k4 = (const float4*)(k + ((size_t)(b * Ss + sj[lane])) * Dd + h * 64);
        const float4* q4 = (const float4*)qsh;
        float s = 0.f;
        #pragma unroll
        for (int d4 = 0; d4 < 16; ++d4) {
            float4 kv = k4[d4];
            float4 qv = q4[d4];
            s += qv.x * kv.x + qv.y * kv.y + qv.z * kv.z + qv.w * kv.w;
        }
        score = s * 0.125f;   // 1/sqrt(64)
    }
    float m = score;
    #pragma unroll
    for (int off = 8; off > 0; off >>= 1) m = fmaxf(m, __shfl_xor(m, off, 16));
    float e = (lane < Kk) ? __expf(score - m) : 0.f;
    float ssum = e;
    #pragma unroll
    for (int off = 8; off > 0; off >>= 1) ssum += __shfl_xor(ssum, off, 16);
    if (lane < Kk) wsh[lane] = e / ssum;
    __syncthreads();

    float o = 0.f;
    #pragma unroll
    for (int j = 0; j < Kk; ++j) {
        const float* vrow = v + ((size_t)(b * Ss + sj[j])) * Dd + h * 64;
        o += wsh[j] * vrow[lane];
    }
    att[((size_t)(b * Ss + i)) * Dd + h * 64 + lane] = (__bf16)o;
}

// ---------------------------------------------------------------------------
// Dense-row attention: the K selected query rows attend over ALL S keys.
// One block per (b, selected-row, h). Writes bf16.
// ---------------------------------------------------------------------------
__global__ void __launch_bounds__(256) attn_dense(
    const float* __restrict__ q, const float* __restrict__ k, const float* __restrict__ v,
    const int* __restrict__ sel_idx, __bf16* __restrict__ att)
{
    int bid = blockIdx.x;
    int h   = bid & (Hh - 1);
    int r   = bid >> 4;
    int kkx = r & (Kk - 1);
    int b   = r >> 4;
    int i   = sel_idx[b * Kk + kkx];
    int t   = threadIdx.x;

    __shared__ __align__(16) float qs[64];
    __shared__ float pbuf[Ss];
    __shared__ float red[256];
    __shared__ float ored[4][64];

    const float* qrow = q + ((size_t)(b * Ss + i)) * Dd + h * 64;
    if (t < 64) qs[t] = qrow[t];
    __syncthreads();

    float lmax = -1e30f;
    const float4* q4 = (const float4*)qs;
    for (int j = t; j < Ss; j += 256) {
        const float4* k4 = (const float4*)(k + ((size_t)(b * Ss + j)) * Dd + h * 64);
        float s = 0.f;
        #pragma unroll
        for (int d4 = 0; d4 < 16; ++d4) {
            float4 kv = k4[d4];
            float4 qv = q4[d4];
            s += qv.x * kv.x + qv.y * kv.y + qv.z * kv.z + qv.w * kv.w;
        }
        s *= 0.125f;
        pbuf[j] = s;
        lmax = fmaxf(lmax, s);
    }
    red[t] = lmax;
    __syncthreads();
    for (int off = 128; off > 0; off >>= 1) {
        if (t < off) red[t] = fmaxf(red[t], red[t + off]);
        __syncthreads();
    }
    float m = red[0];
    __syncthreads();

    float lsum = 0.f;
    for (int j = t; j < Ss; j += 256) {
        float e = __expf(pbuf[j] - m);
        pbuf[j] = e;
        lsum += e;
    }
    red[t] = lsum;
    __syncthreads();
    for (int off = 128; off > 0; off >>= 1) {
        if (t < off) red[t] += red[t + off];
        __syncthreads();
    }
    float inv = 1.0f / red[0];
    __syncthreads();

    int d = t & 63;
    int g = t >> 6;
    float o = 0.f;
    for (int j = g * (Ss / 4); j < (g + 1) * (Ss / 4); ++j)
        o += pbuf[j] * v[((size_t)(b * Ss + j)) * Dd + h * 64 + d];
    ored[g][d] = o;
    __syncthreads();
    if (t < 64) {
        float s = (ored[0][t] + ored[1][t] + ored[2][t] + ored[3][t]) * inv;
        att[((size_t)(b * Ss + i)) * Dd + h * 64 + t] = (__bf16)s;
    }
}

// ---------------------------------------------------------------------------
extern "C" void kernel_launch(void* const* d_in, const int* in_sizes, int n_in,
                              void* d_out, int out_size, void* d_ws, size_t ws_size,
                              hipStream_t stream)
{
    const float* x   = (const float*)d_in[0];
    const float* Wq  = (const float*)d_in[1];
    const float* bq  = (const float*)d_in[2];
    const float* Wk  = (const float*)d_in[3];
    const float* bk  = (const float*)d_in[4];
    const float* Wv  = (const float*)d_in[5];
    const float* bv  = (const float*)d_in[6];
    const float* Wo  = (const float*)d_in[7];
    const float* bo  = (const float*)d_in[8];
    const float* Ws1 = (const float*)d_in[9];
    const float* bs1 = (const float*)d_in[10];
    const float* Ws2 = (const float*)d_in[11];
    const float* bs2 = (const float*)d_in[12];
    float* out = (float*)d_out;

    const size_t MSD = (size_t)Bb * Ss * Dd;   // 4,194,304
    const int M = Bb * Ss;                     // 4096

    char* p = (char*)d_ws;
    float* q    = (float*)p; p += MSD * sizeof(float);
    float* kx   = (float*)p; p += MSD * sizeof(float);
    float* vx   = (float*)p; p += MSD * sizeof(float);
    float* Hs   = (float*)p; p += (size_t)M * 512 * sizeof(float);   // 8 MB
    __bf16* xb  = (__bf16*)p; p += MSD * sizeof(__bf16);
    __bf16* xlo = (__bf16*)p; p += MSD * sizeof(__bf16);
    __bf16* WqT = (__bf16*)p; p += (size_t)Dd * Dd * sizeof(__bf16);
    __bf16* WkT = (__bf16*)p; p += (size_t)Dd * Dd * sizeof(__bf16);
    __bf16* WvT = (__bf16*)p; p += (size_t)Dd * Dd * sizeof(__bf16);
    __bf16* WoT = (__bf16*)p; p += (size_t)Dd * Dd * sizeof(__bf16);
    __bf16* W1Th = (__bf16*)p; p += (size_t)512 * Dd * sizeof(__bf16);
    __bf16* W1Tl = (__bf16*)p; p += (size_t)512 * Dd * sizeof(__bf16);
    float* imp  = (float*)p; p += (size_t)Bb * Ss * sizeof(float);
    int* sel_idx = (int*)p; p += (size_t)Bb * Kk * sizeof(int);
    int* is_sel  = (int*)p; p += (size_t)Bb * Ss * sizeof(int);
    __bf16* att_bf = (__bf16*)Hs;   // alias: Hs dead after imp_kernel

    // 1) Pack inputs: x -> bf16 hi/lo; weights -> transposed bf16.
    pack_x_hilo<<<dim3((int)(MSD / 4 / 256)), 256, 0, stream>>>(x, xb, xlo);
    transpose_pack<<<dim3(32, 32, 4), 256, 0, stream>>>(Wq, Wk, Wv, Wo, WqT, WkT, WvT, WoT);
    transpose_pack_hilo<<<dim3(16, 32), 256, 0, stream>>>(Ws1, W1Th, W1Tl);
    // 2) Indexer hidden via split-precision MFMA (top-k-exact), relu fused.
    gemm_hilo<<<dim3(8, 32), 256, 0, stream>>>(xb, xlo, W1Th, W1Tl, bs1, Hs, M, 512, Dd);
    imp_kernel<<<dim3(M / 4), 256, 0, stream>>>(Hs, Ws2, bs2, imp);
    topk_kernel<<<dim3(Bb), 256, 0, stream>>>(imp, sel_idx, is_sel);
    // 3) QKV projections, bf16 MFMA, z-fused.
    gemm_bf16<<<dim3(8, 32, 3), 256, 0, stream>>>(
        xb, WqT, WkT, WvT, bq, bk, bv, q, kx, vx, M, Dd, Dd);
    // 4) Attention (f32 in, bf16 out).
    attn_sparse<<<dim3(Bb * Ss * Hh), 64, 0, stream>>>(q, kx, vx, sel_idx, is_sel, att_bf);
    attn_dense<<<dim3(Bb * Kk * Hh), 256, 0, stream>>>(q, kx, vx, sel_idx, att_bf);
    // 5) Output projection, bf16 MFMA.
    gemm_bf16<<<dim3(8, 32, 1), 256, 0, stream>>>(
        att_bf, WoT, WoT, WoT, bo, bo, bo, out, out, out, M, Dd, Dd);
}

// Round 4
// 313.595 us; speedup vs baseline: 2.5221x; 1.1549x over previous
//
#include <hip/hip_runtime.h>
#include <math.h>

// Problem constants
constexpr int Bb = 2, Ss = 2048, Dd = 1024, Hh = 16, Kk = 16;

typedef __bf16 bf16x8 __attribute__((ext_vector_type(8)));
typedef __bf16 bf16x4 __attribute__((ext_vector_type(4)));
typedef float  f32x4  __attribute__((ext_vector_type(4)));

__device__ __forceinline__ void gld_lds16(const void* g, void* l) {
    __builtin_amdgcn_global_load_lds(
        (const __attribute__((address_space(1))) unsigned int*)g,
        (__attribute__((address_space(3))) unsigned int*)l, 16, 0, 0);
}

// ---------------------------------------------------------------------------
// bf16 MFMA GEMM (m97 structure): C = A @ BT^T + bias, TO out (f32 or bf16).
// A:[M,K] bf16 row-major. BT:[N,K] bf16 row-major (pre-transposed weights).
// 128x128 tile, BK=32, 4 waves, each wave a 64x64 quadrant via 4x4 of
// 16x16x32 MFMA. Staging via global_load_lds width=16 (lane-linear LDS).
// blockIdx.z selects among up to 3 (BT, bias, C) triples (QKV fusion).
// ---------------------------------------------------------------------------
template<typename TO>
__global__ void __launch_bounds__(256) gemm_bf16(
    const __bf16* __restrict__ A,
    const __bf16* __restrict__ BT0, const __bf16* __restrict__ BT1, const __bf16* __restrict__ BT2,
    const float* __restrict__ b0, const float* __restrict__ b1, const float* __restrict__ b2,
    TO* __restrict__ C0, TO* __restrict__ C1, TO* __restrict__ C2,
    int M, int N, int K)
{
    const __bf16* BT  = (blockIdx.z == 0) ? BT0 : (blockIdx.z == 1) ? BT1 : BT2;
    const float* bias = (blockIdx.z == 0) ? b0  : (blockIdx.z == 1) ? b1  : b2;
    TO*          C    = (blockIdx.z == 0) ? C0  : (blockIdx.z == 1) ? C1  : C2;

    __shared__ __bf16 As[128 * 32];   // lane-linear: chunk c -> bytes [16c,16c+16)
    __shared__ __bf16 Bs[128 * 32];

    const int t    = threadIdx.x;
    const int wave = t >> 6;
    const int lane = t & 63;
    const int bm   = blockIdx.y * 128;
    const int bn   = blockIdx.x * 128;
    const int wm   = (wave & 1) * 64;
    const int wn   = (wave >> 1) * 64;
    const int fr   = lane & 15;        // fragment row (m / n)
    const int fq   = lane >> 4;        // quad -> k offset fq*8

    f32x4 acc[4][4] = {};

    for (int k0 = 0; k0 < K; k0 += 32) {
        #pragma unroll
        for (int l = 0; l < 2; ++l) {
            int c = l * 256 + t;                       // chunk 0..511
            const __bf16* ga = A + (size_t)(bm + (c >> 2)) * K + k0 + (c & 3) * 8;
            gld_lds16(ga, As + (size_t)(l * 256 + wave * 64) * 8);
            const __bf16* gb = BT + (size_t)(bn + (c >> 2)) * K + k0 + (c & 3) * 8;
            gld_lds16(gb, Bs + (size_t)(l * 256 + wave * 64) * 8);
        }
        __syncthreads();

        bf16x8 af[4], bf[4];
        #pragma unroll
        for (int i = 0; i < 4; ++i)
            af[i] = *(const bf16x8*)(As + (wm + i * 16 + fr) * 32 + fq * 8);
        #pragma unroll
        for (int j = 0; j < 4; ++j)
            bf[j] = *(const bf16x8*)(Bs + (wn + j * 16 + fr) * 32 + fq * 8);
        #pragma unroll
        for (int i = 0; i < 4; ++i)
            #pragma unroll
            for (int j = 0; j < 4; ++j)
                acc[i][j] = __builtin_amdgcn_mfma_f32_16x16x32_bf16(af[i], bf[j], acc[i][j], 0, 0, 0);
        __syncthreads();
    }

    // Epilogue. C/D layout: col = lane&15, row = (lane>>4)*4 + reg.
    const int cr = (lane >> 4) * 4;
    const int cc = lane & 15;
    #pragma unroll
    for (int j = 0; j < 4; ++j) {
        int col = bn + wn + j * 16 + cc;
        float bb = bias[col];
        #pragma unroll
        for (int i = 0; i < 4; ++i) {
            #pragma unroll
            for (int r = 0; r < 4; ++r)
                C[(size_t)(bm + wm + i * 16 + cr + r) * N + col] = (TO)(acc[i][j][r] + bb);
        }
    }
}

// ---------------------------------------------------------------------------
// Split-precision indexer GEMM + FUSED importance epilogue:
//   h = x_hi@W_hi + x_hi@W_lo + x_lo@W_hi + bs1   (f32, top-k-exact split)
//   imp[row] += sum_cols relu(h)*Ws2[col]         (atomicAdd, f32)
// bs2 and sigmoid dropped: both monotone => identical top-k set. Atomic
// reorder noise ~1e-7 << rank gap ~3e-3.
// Tile 128x64, BK=32, 4 waves each 64x32 (4x2 frags). Grid 8x32 = 256 blocks.
// ---------------------------------------------------------------------------
__global__ void __launch_bounds__(256) gemm_hilo(
    const __bf16* __restrict__ Ah_g, const __bf16* __restrict__ Al_g,
    const __bf16* __restrict__ Bh_g, const __bf16* __restrict__ Bl_g,
    const float* __restrict__ bs1, const float* __restrict__ Ws2,
    float* __restrict__ imp, int M, int N, int K)
{
    __shared__ __bf16 Ah[128 * 32];
    __shared__ __bf16 Al[128 * 32];
    __shared__ __bf16 Bh[64 * 32];
    __shared__ __bf16 Bl[64 * 32];

    const int t    = threadIdx.x;
    const int wave = t >> 6;
    const int lane = t & 63;
    const int bm   = blockIdx.y * 128;
    const int bn   = blockIdx.x * 64;
    const int wm   = (wave & 1) * 64;
    const int wn   = (wave >> 1) * 32;
    const int fr   = lane & 15;
    const int fq   = lane >> 4;

    f32x4 acc[4][2] = {};

    for (int k0 = 0; k0 < K; k0 += 32) {
        #pragma unroll
        for (int l = 0; l < 2; ++l) {
            int c = l * 256 + t;                       // A chunks 0..511
            size_t goff = (size_t)(bm + (c >> 2)) * K + k0 + (c & 3) * 8;
            gld_lds16(Ah_g + goff, Ah + (size_t)(l * 256 + wave * 64) * 8);
            gld_lds16(Al_g + goff, Al + (size_t)(l * 256 + wave * 64) * 8);
        }
        {
            int c = t;                                 // B chunks 0..255
            size_t goff = (size_t)(bn + (c >> 2)) * K + k0 + (c & 3) * 8;
            gld_lds16(Bh_g + goff, Bh + (size_t)(wave * 64) * 8);
            gld_lds16(Bl_g + goff, Bl + (size_t)(wave * 64) * 8);
        }
        __syncthreads();

        bf16x8 ah[4], al[4], bh[2], bl[2];
        #pragma unroll
        for (int i = 0; i < 4; ++i) {
            ah[i] = *(const bf16x8*)(Ah + (wm + i * 16 + fr) * 32 + fq * 8);
            al[i] = *(const bf16x8*)(Al + (wm + i * 16 + fr) * 32 + fq * 8);
        }
        #pragma unroll
        for (int j = 0; j < 2; ++j) {
            bh[j] = *(const bf16x8*)(Bh + (wn + j * 16 + fr) * 32 + fq * 8);
            bl[j] = *(const bf16x8*)(Bl + (wn + j * 16 + fr) * 32 + fq * 8);
        }
        #pragma unroll
        for (int i = 0; i < 4; ++i)
            #pragma unroll
            for (int j = 0; j < 2; ++j) {
                acc[i][j] = __builtin_amdgcn_mfma_f32_16x16x32_bf16(al[i], bh[j], acc[i][j], 0, 0, 0);
                acc[i][j] = __builtin_amdgcn_mfma_f32_16x16x32_bf16(ah[i], bl[j], acc[i][j], 0, 0, 0);
                acc[i][j] = __builtin_amdgcn_mfma_f32_16x16x32_bf16(ah[i], bh[j], acc[i][j], 0, 0, 0);
            }
        __syncthreads();
    }

    // Fused epilogue: relu(h)*Ws2, reduce 16 cc-lanes, atomicAdd per row.
    const int cr = (lane >> 4) * 4;
    const int cc = lane & 15;
    float bb[2], w2[2];
    #pragma unroll
    for (int j = 0; j < 2; ++j) {
        int col = bn + wn + j * 16 + cc;
        bb[j] = bs1[col];
        w2[j] = Ws2[col];
    }
    #pragma unroll
    for (int i = 0; i < 4; ++i) {
        #pragma unroll
        for (int r = 0; r < 4; ++r) {
            float vsum = fmaxf(acc[i][0][r] + bb[0], 0.f) * w2[0]
                       + fmaxf(acc[i][1][r] + bb[1], 0.f) * w2[1];
            #pragma unroll
            for (int off = 8; off > 0; off >>= 1)
                vsum += __shfl_xor(vsum, off, 16);
            if (cc == 0)
                atomicAdd(imp + (bm + wm + i * 16 + cr + r), vsum);
        }
    }
}

// ---------------------------------------------------------------------------
// Pack x (f32 -> bf16 hi + lo residual), float4-vectorized. Also zero-inits
// imp (atomicAdd target) in the first 16 blocks.
// ---------------------------------------------------------------------------
__global__ void __launch_bounds__(256) pack_x_hilo(
    const float* __restrict__ src, __bf16* __restrict__ hi, __bf16* __restrict__ lo,
    float* __restrict__ imp)
{
    int i = blockIdx.x * 256 + threadIdx.x;
    if (blockIdx.x < 16) imp[i] = 0.f;   // Bb*Ss = 4096 = 16*256
    float4 v = ((const float4*)src)[i];
    bf16x4 h = { (__bf16)v.x, (__bf16)v.y, (__bf16)v.z, (__bf16)v.w };
    bf16x4 l = { (__bf16)(v.x - (float)h[0]), (__bf16)(v.y - (float)h[1]),
                 (__bf16)(v.z - (float)h[2]), (__bf16)(v.w - (float)h[3]) };
    ((bf16x4*)hi)[i] = h;
    ((bf16x4*)lo)[i] = l;
}

// ---------------------------------------------------------------------------
// Transpose + pack weights: WT[n][k] = bf16(W[k][n]), 1024x1024, z = which W.
// ---------------------------------------------------------------------------
__global__ void __launch_bounds__(256) transpose_pack(
    const float* __restrict__ W0, const float* __restrict__ W1,
    const float* __restrict__ W2, const float* __restrict__ W3,
    __bf16* __restrict__ T0, __bf16* __restrict__ T1,
    __bf16* __restrict__ T2, __bf16* __restrict__ T3)
{
    const float* W = (blockIdx.z == 0) ? W0 : (blockIdx.z == 1) ? W1 : (blockIdx.z == 2) ? W2 : W3;
    __bf16*      T = (blockIdx.z == 0) ? T0 : (blockIdx.z == 1) ? T1 : (blockIdx.z == 2) ? T2 : T3;

    __shared__ float tile[32][33];
    int tx = threadIdx.x & 31, ty = threadIdx.x >> 5;   // 32 x 8
    int n0 = blockIdx.x * 32, k0 = blockIdx.y * 32;
    #pragma unroll
    for (int i = 0; i < 32; i += 8)
        tile[ty + i][tx] = W[(size_t)(k0 + ty + i) * 1024 + n0 + tx];
    __syncthreads();
    #pragma unroll
    for (int i = 0; i < 32; i += 8)
        T[(size_t)(n0 + ty + i) * 1024 + k0 + tx] = (__bf16)tile[tx][ty + i];
}

// ---------------------------------------------------------------------------
// Transpose + hi/lo pack Ws1: [1024, 512] f32 -> Th/Tl [512][1024] bf16.
// ---------------------------------------------------------------------------
__global__ void __launch_bounds__(256) transpose_pack_hilo(
    const float* __restrict__ W, __bf16* __restrict__ Th, __bf16* __restrict__ Tl)
{
    __shared__ float tile[32][33];
    int tx = threadIdx.x & 31, ty = threadIdx.x >> 5;   // 32 x 8
    int n0 = blockIdx.x * 32, k0 = blockIdx.y * 32;
    #pragma unroll
    for (int i = 0; i < 32; i += 8)
        tile[ty + i][tx] = W[(size_t)(k0 + ty + i) * 512 + n0 + tx];
    __syncthreads();
    #pragma unroll
    for (int i = 0; i < 32; i += 8) {
        float v = tile[tx][ty + i];
        __bf16 h = (__bf16)v;
        Th[(size_t)(n0 + ty + i) * 1024 + k0 + tx] = h;
        Tl[(size_t)(n0 + ty + i) * 1024 + k0 + tx] = (__bf16)(v - (float)h);
    }
}

// ---------------------------------------------------------------------------
// Exact top-K per batch via K iterative argmax passes.
// ---------------------------------------------------------------------------
__global__ void __launch_bounds__(256) topk_kernel(
    const float* __restrict__ imp, int* __restrict__ sel_idx)
{
    int b = blockIdx.x;
    int t = threadIdx.x;
    __shared__ float vals[Ss];
    __shared__ float sv[256];
    __shared__ int   si[256];

    for (int j = t; j < Ss; j += 256) vals[j] = imp[b * Ss + j];
    __syncthreads();

    for (int it = 0; it < Kk; ++it) {
        float best = -1e30f; int bidx = 0x7fffffff;
        for (int j = t; j < Ss; j += 256) {
            float v = vals[j];
            if (v > best || (v == best && j < bidx)) { best = v; bidx = j; }
        }
        sv[t] = best; si[t] = bidx;
        __syncthreads();
        for (int off = 128; off > 0; off >>= 1) {
            if (t < off) {
                float ov = sv[t + off]; int oi = si[t + off];
                if (ov > sv[t] || (ov == sv[t] && oi < si[t])) { sv[t] = ov; si[t] = oi; }
            }
            __syncthreads();
        }
        if (t == 0) {
            sel_idx[b * Kk + it] = si[0];
            vals[si[0]] = -1e30f;
        }
        __syncthreads();
    }
}

// ---------------------------------------------------------------------------
// Sparse attention v2: ALL rows attend over the 16 selected keys (the 16
// selected rows are overwritten by attn_dense afterwards). One 256-thread
// block per (b, h, 16 queries); K^T/V/Q staged in LDS; all 64 lanes active
// (wave = 4 queries x 16 keys). Grid 128 x 16 x 2 = 4096 blocks.
// ---------------------------------------------------------------------------
__global__ void __launch_bounds__(256) attn_sparse(
    const __bf16* __restrict__ q, const __bf16* __restrict__ k,
    const __bf16* __restrict__ v, const int* __restrict__ sel_idx,
    __bf16* __restrict__ att)
{
    const int b  = blockIdx.z;
    const int h  = blockIdx.y;
    const int q0 = blockIdx.x * 16;
    const int t  = threadIdx.x;

    __shared__ float KT[64][17];     // KT[d][j], padded
    __shared__ float Vs[16][64];
    __shared__ float qsh[16][65];
    __shared__ float wsh[16][16];
    __shared__ int   sj[16];

    if (t < 16) sj[t] = sel_idx[b * Kk + t];
    __syncthreads();

    {   // stage K, V (16 selected rows) and Q (16 query rows)
        int row = t >> 4, d0 = (t & 15) * 4;
        bf16x4 kv = *(const bf16x4*)(k + ((size_t)(b * Ss + sj[row])) * Dd + h * 64 + d0);
        bf16x4 vv = *(const bf16x4*)(v + ((size_t)(b * Ss + sj[row])) * Dd + h * 64 + d0);
        bf16x4 qv = *(const bf16x4*)(q + ((size_t)(b * Ss + q0 + row)) * Dd + h * 64 + d0);
        #pragma unroll
        for (int i = 0; i < 4; ++i) {
            KT[d0 + i][row]  = (float)kv[i];
            Vs[row][d0 + i]  = (float)vv[i];
            qsh[row][d0 + i] = (float)qv[i];
        }
    }
    __syncthreads();

    const int wave = t >> 6, lane = t & 63;
    const int ql = lane >> 4, j = lane & 15;
    const int qi = wave * 4 + ql;

    // scores: lane computes full 64-dot for (query qi, key j)
    float s = 0.f;
    #pragma unroll
    for (int d = 0; d < 64; ++d) s = fmaf(qsh[qi][d], KT[d][j], s);
    s *= 0.125f;   // 1/sqrt(64)

    // softmax across the 16 j-lanes
    float m = s;
    #pragma unroll
    for (int off = 8; off > 0; off >>= 1) m = fmaxf(m, __shfl_xor(m, off, 16));
    float e = __expf(s - m);
    float sum = e;
    #pragma unroll
    for (int off = 8; off > 0; off >>= 1) sum += __shfl_xor(sum, off, 16);
    wsh[qi][j] = e / sum;   // read back only by this wave: no barrier needed

    // output: O[qi][d] = sum_j w * V[j][d]; lane owns dim d = lane
    #pragma unroll
    for (int q2 = 0; q2 < 4; ++q2) {
        int qq = wave * 4 + q2;
        float o = 0.f;
        #pragma unroll
        for (int jj = 0; jj < 16; ++jj)
            o = fmaf(wsh[qq][jj], Vs[jj][lane], o);
        att[((size_t)(b * Ss + q0 + qq)) * Dd + h * 64 + lane] = (__bf16)o;
    }
}

// ---------------------------------------------------------------------------
// Dense-row attention: the K selected query rows attend over ALL S keys.
// One block per (b, selected-row, h). bf16 in, bf16 out.
// ---------------------------------------------------------------------------
__global__ void __launch_bounds__(256) attn_dense(
    const __bf16* __restrict__ q, const __bf16* __restrict__ k,
    const __bf16* __restrict__ v, const int* __restrict__ sel_idx,
    __bf16* __restrict__ att)
{
    int bid = blockIdx.x;
    int h   = bid & (Hh - 1);
    int r   = bid >> 4;
    int kkx = r & (Kk - 1);
    int b   = r >> 4;
    int i   = sel_idx[b * Kk + kkx];
    int t   = threadIdx.x;

    __shared__ float qs[64];
    __shared__ float pbuf[Ss];
    __shared__ float red[256];
    __shared__ float ored[4][64];

    if (t < 64) qs[t] = (float)q[((size_t)(b * Ss + i)) * Dd + h * 64 + t];
    __syncthreads();

    float lmax = -1e30f;
    for (int j = t; j < Ss; j += 256) {
        const bf16x8* k8 = (const bf16x8*)(k + ((size_t)(b * Ss + j)) * Dd + h * 64);
        float s = 0.f;
        #pragma unroll
        for (int c = 0; c < 8; ++c) {
            bf16x8 kv = k8[c];
            #pragma unroll
            for (int e = 0; e < 8; ++e) s = fmaf(qs[c * 8 + e], (float)kv[e], s);
        }
        s *= 0.125f;
        pbuf[j] = s;
        lmax = fmaxf(lmax, s);
    }
    red[t] = lmax;
    __syncthreads();
    for (int off = 128; off > 0; off >>= 1) {
        if (t < off) red[t] = fmaxf(red[t], red[t + off]);
        __syncthreads();
    }
    float m = red[0];
    __syncthreads();

    float lsum = 0.f;
    for (int j = t; j < Ss; j += 256) {
        float e = __expf(pbuf[j] - m);
        pbuf[j] = e;
        lsum += e;
    }
    red[t] = lsum;
    __syncthreads();
    for (int off = 128; off > 0; off >>= 1) {
        if (t < off) red[t] += red[t + off];
        __syncthreads();
    }
    float inv = 1.0f / red[0];
    __syncthreads();

    int d = t & 63;
    int g = t >> 6;
    float o = 0.f;
    for (int j = g * (Ss / 4); j < (g + 1) * (Ss / 4); ++j)
        o = fmaf(pbuf[j], (float)v[((size_t)(b * Ss + j)) * Dd + h * 64 + d], o);
    ored[g][d] = o;
    __syncthreads();
    if (t < 64) {
        float s = (ored[0][t] + ored[1][t] + ored[2][t] + ored[3][t]) * inv;
        att[((size_t)(b * Ss + i)) * Dd + h * 64 + t] = (__bf16)s;
    }
}

// ---------------------------------------------------------------------------
extern "C" void kernel_launch(void* const* d_in, const int* in_sizes, int n_in,
                              void* d_out, int out_size, void* d_ws, size_t ws_size,
                              hipStream_t stream)
{
    const float* x   = (const float*)d_in[0];
    const float* Wq  = (const float*)d_in[1];
    const float* bq  = (const float*)d_in[2];
    const float* Wk  = (const float*)d_in[3];
    const float* bk  = (const float*)d_in[4];
    const float* Wv  = (const float*)d_in[5];
    const float* bv  = (const float*)d_in[6];
    const float* Wo  = (const float*)d_in[7];
    const float* bo  = (const float*)d_in[8];
    const float* Ws1 = (const float*)d_in[9];
    const float* bs1 = (const float*)d_in[10];
    const float* Ws2 = (const float*)d_in[11];
    float* out = (float*)d_out;

    const size_t MSD = (size_t)Bb * Ss * Dd;   // 4,194,304
    const int M = Bb * Ss;                     // 4096

    char* p = (char*)d_ws;
    __bf16* qb  = (__bf16*)p; p += MSD * sizeof(__bf16);
    __bf16* kb  = (__bf16*)p; p += MSD * sizeof(__bf16);
    __bf16* vb  = (__bf16*)p; p += MSD * sizeof(__bf16);
    __bf16* att = (__bf16*)p; p += MSD * sizeof(__bf16);
    __bf16* xb  = (__bf16*)p; p += MSD * sizeof(__bf16);
    __bf16* xlo = (__bf16*)p; p += MSD * sizeof(__bf16);
    __bf16* WqT = (__bf16*)p; p += (size_t)Dd * Dd * sizeof(__bf16);
    __bf16* WkT = (__bf16*)p; p += (size_t)Dd * Dd * sizeof(__bf16);
    __bf16* WvT = (__bf16*)p; p += (size_t)Dd * Dd * sizeof(__bf16);
    __bf16* WoT = (__bf16*)p; p += (size_t)Dd * Dd * sizeof(__bf16);
    __bf16* W1Th = (__bf16*)p; p += (size_t)512 * Dd * sizeof(__bf16);
    __bf16* W1Tl = (__bf16*)p; p += (size_t)512 * Dd * sizeof(__bf16);
    float* imp  = (float*)p; p += (size_t)Bb * Ss * sizeof(float);
    int* sel_idx = (int*)p; p += (size_t)Bb * Kk * sizeof(int);

    // 1) Pack inputs: x -> bf16 hi/lo (+ zero imp); weights -> transposed bf16.
    pack_x_hilo<<<dim3((int)(MSD / 4 / 256)), 256, 0, stream>>>(x, xb, xlo, imp);
    transpose_pack<<<dim3(32, 32, 4), 256, 0, stream>>>(Wq, Wk, Wv, Wo, WqT, WkT, WvT, WoT);
    transpose_pack_hilo<<<dim3(16, 32), 256, 0, stream>>>(Ws1, W1Th, W1Tl);
    // 2) Indexer: split-precision MFMA with fused relu*Ws2 atomic epilogue.
    gemm_hilo<<<dim3(8, 32), 256, 0, stream>>>(xb, xlo, W1Th, W1Tl, bs1, Ws2, imp, M, 512, Dd);
    topk_kernel<<<dim3(Bb), 256, 0, stream>>>(imp, sel_idx);
    // 3) QKV projections, bf16 MFMA, bf16 outputs.
    gemm_bf16<__bf16><<<dim3(8, 32, 3), 256, 0, stream>>>(
        xb, WqT, WkT, WvT, bq, bk, bv, qb, kb, vb, M, Dd, Dd);
    // 4) Attention: sparse writes all rows; dense overwrites the 16 selected.
    attn_sparse<<<dim3(Ss / 16, Hh, Bb), 256, 0, stream>>>(qb, kb, vb, sel_idx, att);
    attn_dense<<<dim3(Bb * Kk * Hh), 256, 0, stream>>>(qb, kb, vb, sel_idx, att);
    // 5) Output projection, bf16 MFMA, f32 out.
    gemm_bf16<float><<<dim3(8, 32, 1), 256, 0, stream>>>(
        att, WoT, WoT, WoT, bo, bo, bo, out, out, out, M, Dd, Dd);
}

// Round 5
// 281.549 us; speedup vs baseline: 2.8092x; 1.1138x over previous
//
#include <hip/hip_runtime.h>
#include <math.h>

// Problem constants
constexpr int Bb = 2, Ss = 2048, Dd = 1024, Hh = 16, Kk = 16;

typedef __bf16 bf16x8 __attribute__((ext_vector_type(8)));
typedef __bf16 bf16x4 __attribute__((ext_vector_type(4)));
typedef float  f32x4  __attribute__((ext_vector_type(4)));

__device__ __forceinline__ void gld_lds16(const void* g, void* l) {
    __builtin_amdgcn_global_load_lds(
        (const __attribute__((address_space(1))) unsigned int*)g,
        (__attribute__((address_space(3))) unsigned int*)l, 16, 0, 0);
}

// Ordered map for f32 atomicMax on uint (monotone bijection).
__device__ __forceinline__ unsigned fmap(float f) {
    unsigned u = __float_as_uint(f);
    return (u & 0x80000000u) ? ~u : (u | 0x80000000u);
}
__device__ __forceinline__ float funmap(unsigned u) {
    return (u & 0x80000000u) ? __uint_as_float(u ^ 0x80000000u) : __uint_as_float(~u);
}

// ---------------------------------------------------------------------------
// bf16 MFMA GEMM (m97 structure): C = A @ BT^T + bias, TO out (f32 or bf16).
// ---------------------------------------------------------------------------
template<typename TO>
__global__ void __launch_bounds__(256) gemm_bf16(
    const __bf16* __restrict__ A,
    const __bf16* __restrict__ BT0, const __bf16* __restrict__ BT1, const __bf16* __restrict__ BT2,
    const float* __restrict__ b0, const float* __restrict__ b1, const float* __restrict__ b2,
    TO* __restrict__ C0, TO* __restrict__ C1, TO* __restrict__ C2,
    int M, int N, int K)
{
    const __bf16* BT  = (blockIdx.z == 0) ? BT0 : (blockIdx.z == 1) ? BT1 : BT2;
    const float* bias = (blockIdx.z == 0) ? b0  : (blockIdx.z == 1) ? b1  : b2;
    TO*          C    = (blockIdx.z == 0) ? C0  : (blockIdx.z == 1) ? C1  : C2;

    __shared__ __bf16 As[128 * 32];
    __shared__ __bf16 Bs[128 * 32];

    const int t    = threadIdx.x;
    const int wave = t >> 6;
    const int lane = t & 63;
    const int bm   = blockIdx.y * 128;
    const int bn   = blockIdx.x * 128;
    const int wm   = (wave & 1) * 64;
    const int wn   = (wave >> 1) * 64;
    const int fr   = lane & 15;
    const int fq   = lane >> 4;

    f32x4 acc[4][4] = {};

    for (int k0 = 0; k0 < K; k0 += 32) {
        #pragma unroll
        for (int l = 0; l < 2; ++l) {
            int c = l * 256 + t;
            const __bf16* ga = A + (size_t)(bm + (c >> 2)) * K + k0 + (c & 3) * 8;
            gld_lds16(ga, As + (size_t)(l * 256 + wave * 64) * 8);
            const __bf16* gb = BT + (size_t)(bn + (c >> 2)) * K + k0 + (c & 3) * 8;
            gld_lds16(gb, Bs + (size_t)(l * 256 + wave * 64) * 8);
        }
        __syncthreads();

        bf16x8 af[4], bf[4];
        #pragma unroll
        for (int i = 0; i < 4; ++i)
            af[i] = *(const bf16x8*)(As + (wm + i * 16 + fr) * 32 + fq * 8);
        #pragma unroll
        for (int j = 0; j < 4; ++j)
            bf[j] = *(const bf16x8*)(Bs + (wn + j * 16 + fr) * 32 + fq * 8);
        #pragma unroll
        for (int i = 0; i < 4; ++i)
            #pragma unroll
            for (int j = 0; j < 4; ++j)
                acc[i][j] = __builtin_amdgcn_mfma_f32_16x16x32_bf16(af[i], bf[j], acc[i][j], 0, 0, 0);
        __syncthreads();
    }

    const int cr = (lane >> 4) * 4;
    const int cc = lane & 15;
    #pragma unroll
    for (int j = 0; j < 4; ++j) {
        int col = bn + wn + j * 16 + cc;
        float bb = bias[col];
        #pragma unroll
        for (int i = 0; i < 4; ++i) {
            #pragma unroll
            for (int r = 0; r < 4; ++r)
                C[(size_t)(bm + wm + i * 16 + cr + r) * N + col] = (TO)(acc[i][j][r] + bb);
        }
    }
}

// ---------------------------------------------------------------------------
// Split-precision indexer GEMM + fused relu*Ws2 atomic epilogue (top-k-exact).
// ---------------------------------------------------------------------------
__global__ void __launch_bounds__(256) gemm_hilo(
    const __bf16* __restrict__ Ah_g, const __bf16* __restrict__ Al_g,
    const __bf16* __restrict__ Bh_g, const __bf16* __restrict__ Bl_g,
    const float* __restrict__ bs1, const float* __restrict__ Ws2,
    float* __restrict__ imp, int M, int N, int K)
{
    __shared__ __bf16 Ah[128 * 32];
    __shared__ __bf16 Al[128 * 32];
    __shared__ __bf16 Bh[64 * 32];
    __shared__ __bf16 Bl[64 * 32];

    const int t    = threadIdx.x;
    const int wave = t >> 6;
    const int lane = t & 63;
    const int bm   = blockIdx.y * 128;
    const int bn   = blockIdx.x * 64;
    const int wm   = (wave & 1) * 64;
    const int wn   = (wave >> 1) * 32;
    const int fr   = lane & 15;
    const int fq   = lane >> 4;

    f32x4 acc[4][2] = {};

    for (int k0 = 0; k0 < K; k0 += 32) {
        #pragma unroll
        for (int l = 0; l < 2; ++l) {
            int c = l * 256 + t;
            size_t goff = (size_t)(bm + (c >> 2)) * K + k0 + (c & 3) * 8;
            gld_lds16(Ah_g + goff, Ah + (size_t)(l * 256 + wave * 64) * 8);
            gld_lds16(Al_g + goff, Al + (size_t)(l * 256 + wave * 64) * 8);
        }
        {
            int c = t;
            size_t goff = (size_t)(bn + (c >> 2)) * K + k0 + (c & 3) * 8;
            gld_lds16(Bh_g + goff, Bh + (size_t)(wave * 64) * 8);
            gld_lds16(Bl_g + goff, Bl + (size_t)(wave * 64) * 8);
        }
        __syncthreads();

        bf16x8 ah[4], al[4], bh[2], bl[2];
        #pragma unroll
        for (int i = 0; i < 4; ++i) {
            ah[i] = *(const bf16x8*)(Ah + (wm + i * 16 + fr) * 32 + fq * 8);
            al[i] = *(const bf16x8*)(Al + (wm + i * 16 + fr) * 32 + fq * 8);
        }
        #pragma unroll
        for (int j = 0; j < 2; ++j) {
            bh[j] = *(const bf16x8*)(Bh + (wn + j * 16 + fr) * 32 + fq * 8);
            bl[j] = *(const bf16x8*)(Bl + (wn + j * 16 + fr) * 32 + fq * 8);
        }
        #pragma unroll
        for (int i = 0; i < 4; ++i)
            #pragma unroll
            for (int j = 0; j < 2; ++j) {
                acc[i][j] = __builtin_amdgcn_mfma_f32_16x16x32_bf16(al[i], bh[j], acc[i][j], 0, 0, 0);
                acc[i][j] = __builtin_amdgcn_mfma_f32_16x16x32_bf16(ah[i], bl[j], acc[i][j], 0, 0, 0);
                acc[i][j] = __builtin_amdgcn_mfma_f32_16x16x32_bf16(ah[i], bh[j], acc[i][j], 0, 0, 0);
            }
        __syncthreads();
    }

    const int cr = (lane >> 4) * 4;
    const int cc = lane & 15;
    float bb[2], w2[2];
    #pragma unroll
    for (int j = 0; j < 2; ++j) {
        int col = bn + wn + j * 16 + cc;
        bb[j] = bs1[col];
        w2[j] = Ws2[col];
    }
    #pragma unroll
    for (int i = 0; i < 4; ++i) {
        #pragma unroll
        for (int r = 0; r < 4; ++r) {
            float vsum = fmaxf(acc[i][0][r] + bb[0], 0.f) * w2[0]
                       + fmaxf(acc[i][1][r] + bb[1], 0.f) * w2[1];
            #pragma unroll
            for (int off = 8; off > 0; off >>= 1)
                vsum += __shfl_xor(vsum, off, 16);
            if (cc == 0)
                atomicAdd(imp + (bm + wm + i * 16 + cr + r), vsum);
        }
    }
}

// ---------------------------------------------------------------------------
// Pack x (f32 -> bf16 hi + lo residual). Also zero-inits imp and the dense-
// attention accumulators (oacc 32768, lsum/macc 512 each).
// ---------------------------------------------------------------------------
__global__ void __launch_bounds__(256) pack_x_hilo(
    const float* __restrict__ src, __bf16* __restrict__ hi, __bf16* __restrict__ lo,
    float* __restrict__ imp, float* __restrict__ oacc,
    float* __restrict__ lsum, unsigned* __restrict__ macc)
{
    int i = blockIdx.x * 256 + threadIdx.x;
    if (i < Bb * Ss) imp[i] = 0.f;
    if (i < Bb * Hh * Kk * 64) oacc[i] = 0.f;
    if (i < Bb * Hh * Kk) { lsum[i] = 0.f; macc[i] = 0u; }
    float4 v = ((const float4*)src)[i];
    bf16x4 h = { (__bf16)v.x, (__bf16)v.y, (__bf16)v.z, (__bf16)v.w };
    bf16x4 l = { (__bf16)(v.x - (float)h[0]), (__bf16)(v.y - (float)h[1]),
                 (__bf16)(v.z - (float)h[2]), (__bf16)(v.w - (float)h[3]) };
    ((bf16x4*)hi)[i] = h;
    ((bf16x4*)lo)[i] = l;
}

// ---------------------------------------------------------------------------
// Transpose + pack weights: WT[n][k] = bf16(W[k][n]), 1024x1024, z = which W.
// ---------------------------------------------------------------------------
__global__ void __launch_bounds__(256) transpose_pack(
    const float* __restrict__ W0, const float* __restrict__ W1,
    const float* __restrict__ W2, const float* __restrict__ W3,
    __bf16* __restrict__ T0, __bf16* __restrict__ T1,
    __bf16* __restrict__ T2, __bf16* __restrict__ T3)
{
    const float* W = (blockIdx.z == 0) ? W0 : (blockIdx.z == 1) ? W1 : (blockIdx.z == 2) ? W2 : W3;
    __bf16*      T = (blockIdx.z == 0) ? T0 : (blockIdx.z == 1) ? T1 : (blockIdx.z == 2) ? T2 : T3;

    __shared__ float tile[32][33];
    int tx = threadIdx.x & 31, ty = threadIdx.x >> 5;
    int n0 = blockIdx.x * 32, k0 = blockIdx.y * 32;
    #pragma unroll
    for (int i = 0; i < 32; i += 8)
        tile[ty + i][tx] = W[(size_t)(k0 + ty + i) * 1024 + n0 + tx];
    __syncthreads();
    #pragma unroll
    for (int i = 0; i < 32; i += 8)
        T[(size_t)(n0 + ty + i) * 1024 + k0 + tx] = (__bf16)tile[tx][ty + i];
}

// ---------------------------------------------------------------------------
// Transpose + hi/lo pack Ws1: [1024, 512] f32 -> Th/Tl [512][1024] bf16.
// ---------------------------------------------------------------------------
__global__ void __launch_bounds__(256) transpose_pack_hilo(
    const float* __restrict__ W, __bf16* __restrict__ Th, __bf16* __restrict__ Tl)
{
    __shared__ float tile[32][33];
    int tx = threadIdx.x & 31, ty = threadIdx.x >> 5;
    int n0 = blockIdx.x * 32, k0 = blockIdx.y * 32;
    #pragma unroll
    for (int i = 0; i < 32; i += 8)
        tile[ty + i][tx] = W[(size_t)(k0 + ty + i) * 512 + n0 + tx];
    __syncthreads();
    #pragma unroll
    for (int i = 0; i < 32; i += 8) {
        float v = tile[tx][ty + i];
        __bf16 h = (__bf16)v;
        Th[(size_t)(n0 + ty + i) * 1024 + k0 + tx] = h;
        Tl[(size_t)(n0 + ty + i) * 1024 + k0 + tx] = (__bf16)(v - (float)h);
    }
}

// ---------------------------------------------------------------------------
// Exact top-K per batch via K iterative argmax passes.
// ---------------------------------------------------------------------------
__global__ void __launch_bounds__(256) topk_kernel(
    const float* __restrict__ imp, int* __restrict__ sel_idx)
{
    int b = blockIdx.x;
    int t = threadIdx.x;
    __shared__ float vals[Ss];
    __shared__ float sv[256];
    __shared__ int   si[256];

    for (int j = t; j < Ss; j += 256) vals[j] = imp[b * Ss + j];
    __syncthreads();

    for (int it = 0; it < Kk; ++it) {
        float best = -1e30f; int bidx = 0x7fffffff;
        for (int j = t; j < Ss; j += 256) {
            float v = vals[j];
            if (v > best || (v == best && j < bidx)) { best = v; bidx = j; }
        }
        sv[t] = best; si[t] = bidx;
        __syncthreads();
        for (int off = 128; off > 0; off >>= 1) {
            if (t < off) {
                float ov = sv[t + off]; int oi = si[t + off];
                if (ov > sv[t] || (ov == sv[t] && oi < si[t])) { sv[t] = ov; si[t] = oi; }
            }
            __syncthreads();
        }
        if (t == 0) {
            sel_idx[b * Kk + it] = si[0];
            vals[si[0]] = -1e30f;
        }
        __syncthreads();
    }
}

// ---------------------------------------------------------------------------
// Sparse attention: ALL rows attend over the 16 selected keys (selected rows
// overwritten by dense pipeline). One block per (b, h, 16 queries).
// ---------------------------------------------------------------------------
__global__ void __launch_bounds__(256) attn_sparse(
    const __bf16* __restrict__ q, const __bf16* __restrict__ k,
    const __bf16* __restrict__ v, const int* __restrict__ sel_idx,
    __bf16* __restrict__ att)
{
    const int b  = blockIdx.z;
    const int h  = blockIdx.y;
    const int q0 = blockIdx.x * 16;
    const int t  = threadIdx.x;

    __shared__ float KT[64][17];
    __shared__ float Vs[16][64];
    __shared__ float qsh[16][65];
    __shared__ float wsh[16][16];
    __shared__ int   sj[16];

    if (t < 16) sj[t] = sel_idx[b * Kk + t];
    __syncthreads();

    {
        int row = t >> 4, d0 = (t & 15) * 4;
        bf16x4 kv = *(const bf16x4*)(k + ((size_t)(b * Ss + sj[row])) * Dd + h * 64 + d0);
        bf16x4 vv = *(const bf16x4*)(v + ((size_t)(b * Ss + sj[row])) * Dd + h * 64 + d0);
        bf16x4 qv = *(const bf16x4*)(q + ((size_t)(b * Ss + q0 + row)) * Dd + h * 64 + d0);
        #pragma unroll
        for (int i = 0; i < 4; ++i) {
            KT[d0 + i][row]  = (float)kv[i];
            Vs[row][d0 + i]  = (float)vv[i];
            qsh[row][d0 + i] = (float)qv[i];
        }
    }
    __syncthreads();

    const int wave = t >> 6, lane = t & 63;
    const int ql = lane >> 4, j = lane & 15;
    const int qi = wave * 4 + ql;

    float s = 0.f;
    #pragma unroll
    for (int d = 0; d < 64; ++d) s = fmaf(qsh[qi][d], KT[d][j], s);
    s *= 0.125f;

    float m = s;
    #pragma unroll
    for (int off = 8; off > 0; off >>= 1) m = fmaxf(m, __shfl_xor(m, off, 16));
    float e = __expf(s - m);
    float sum = e;
    #pragma unroll
    for (int off = 8; off > 0; off >>= 1) sum += __shfl_xor(sum, off, 16);
    wsh[qi][j] = e / sum;

    #pragma unroll
    for (int q2 = 0; q2 < 4; ++q2) {
        int qq = wave * 4 + q2;
        float o = 0.f;
        #pragma unroll
        for (int jj = 0; jj < 16; ++jj)
            o = fmaf(wsh[qq][jj], Vs[jj][lane], o);
        att[((size_t)(b * Ss + q0 + qq)) * Dd + h * 64 + lane] = (__bf16)o;
    }
}

// ---------------------------------------------------------------------------
// Dense attention phase 1: scores for 16 selected queries x 128-key chunk.
// Grid (16 chunks, Hh, Bb). Writes f32 scores + per-q global max (atomicMax
// on order-mapped uint - exact, order-independent).
// ---------------------------------------------------------------------------
__global__ void __launch_bounds__(256) attn_dense_qk(
    const __bf16* __restrict__ q, const __bf16* __restrict__ k,
    const int* __restrict__ sel_idx, float* __restrict__ Sbuf,
    unsigned* __restrict__ macc)
{
    const int b  = blockIdx.z, h = blockIdx.y, j0 = blockIdx.x * 128;
    const int t  = threadIdx.x;

    __shared__ float Ks[128][65];
    __shared__ float Qs[16][65];

    #pragma unroll
    for (int l = 0; l < 4; ++l) {            // K chunk: 1024 bf16x8 segs
        int c = t + 256 * l;
        int row = c >> 3, seg = c & 7;
        bf16x8 kv = *(const bf16x8*)(k + ((size_t)(b * Ss + j0 + row)) * Dd + h * 64 + seg * 8);
        #pragma unroll
        for (int e = 0; e < 8; ++e) Ks[row][seg * 8 + e] = (float)kv[e];
    }
    if (t < 128) {                           // Q: 16 rows
        int row = t >> 3, seg = t & 7;
        int i = sel_idx[b * Kk + row];
        bf16x8 qv = *(const bf16x8*)(q + ((size_t)(b * Ss + i)) * Dd + h * 64 + seg * 8);
        #pragma unroll
        for (int e = 0; e < 8; ++e) Qs[row][seg * 8 + e] = (float)qv[e];
    }
    __syncthreads();

    const int qi = t >> 4, ks = t & 15;
    const int bhq = (b * Hh + h) * Kk + qi;
    float lmax = -1e30f;
    #pragma unroll
    for (int s8 = 0; s8 < 8; ++s8) {
        int j = ks + s8 * 16;
        float s = 0.f;
        #pragma unroll
        for (int d = 0; d < 64; ++d) s = fmaf(Qs[qi][d], Ks[j][d], s);
        s *= 0.125f;
        Sbuf[(size_t)bhq * Ss + j0 + j] = s;
        lmax = fmaxf(lmax, s);
    }
    #pragma unroll
    for (int off = 8; off > 0; off >>= 1) lmax = fmaxf(lmax, __shfl_xor(lmax, off, 16));
    if (ks == 0) atomicMax(macc + bhq, fmap(lmax));
}

// ---------------------------------------------------------------------------
// Dense attention phase 2: e = exp(s - m); partial sums to lsum (atomicAdd);
// partial PV to oacc (atomicAdd). Grid (16 chunks, Hh, Bb).
// ---------------------------------------------------------------------------
__global__ void __launch_bounds__(256) attn_dense_pv(
    const __bf16* __restrict__ v, const float* __restrict__ Sbuf,
    const unsigned* __restrict__ macc, float* __restrict__ lsum,
    float* __restrict__ oacc)
{
    const int b  = blockIdx.z, h = blockIdx.y, j0 = blockIdx.x * 128;
    const int t  = threadIdx.x;

    __shared__ float Vs[128][64];    // lanes read consecutive d: 2-way, free
    __shared__ float Es[16][144];    // pad 144: writes spread banks

    #pragma unroll
    for (int l = 0; l < 4; ++l) {
        int c = t + 256 * l;
        int row = c >> 3, seg = c & 7;
        bf16x8 vv = *(const bf16x8*)(v + ((size_t)(b * Ss + j0 + row)) * Dd + h * 64 + seg * 8);
        #pragma unroll
        for (int e = 0; e < 8; ++e) Vs[row][seg * 8 + e] = (float)vv[e];
    }

    const int qi = t >> 4, ks = t & 15;
    const int bhq = (b * Hh + h) * Kk + qi;
    const float mq = funmap(macc[bhq]);
    float psum = 0.f;
    #pragma unroll
    for (int s8 = 0; s8 < 8; ++s8) {
        int j = ks + s8 * 16;
        float e = __expf(Sbuf[(size_t)bhq * Ss + j0 + j] - mq);
        Es[qi][j] = e;
        psum += e;
    }
    #pragma unroll
    for (int off = 8; off > 0; off >>= 1) psum += __shfl_xor(psum, off, 16);
    if (ks == 0) atomicAdd(lsum + bhq, psum);
    __syncthreads();

    const int d = t & 63, qg = t >> 6;
    #pragma unroll
    for (int qq = 0; qq < 4; ++qq) {
        int qx = qg * 4 + qq;
        float o = 0.f;
        #pragma unroll 4
        for (int jj = 0; jj < 128; ++jj)
            o = fmaf(Es[qx][jj], Vs[jj][d], o);
        atomicAdd(oacc + (size_t)((b * Hh + h) * Kk + qx) * 64 + d, o);
    }
}

// ---------------------------------------------------------------------------
// Dense attention phase 3: att[selected rows] = oacc / lsum.
// Grid 512 blocks x 64 threads.
// ---------------------------------------------------------------------------
__global__ void __launch_bounds__(64) attn_dense_fin(
    const float* __restrict__ oacc, const float* __restrict__ lsum,
    const int* __restrict__ sel_idx, __bf16* __restrict__ att)
{
    int bid = blockIdx.x;
    int qi = bid & 15, h = (bid >> 4) & 15, b = bid >> 8;
    int bhq = (b * Hh + h) * Kk + qi;
    int i = sel_idx[b * Kk + qi];
    float val = oacc[(size_t)bhq * 64 + threadIdx.x] / lsum[bhq];
    att[((size_t)(b * Ss + i)) * Dd + h * 64 + threadIdx.x] = (__bf16)val;
}

// ---------------------------------------------------------------------------
extern "C" void kernel_launch(void* const* d_in, const int* in_sizes, int n_in,
                              void* d_out, int out_size, void* d_ws, size_t ws_size,
                              hipStream_t stream)
{
    const float* x   = (const float*)d_in[0];
    const float* Wq  = (const float*)d_in[1];
    const float* bq  = (const float*)d_in[2];
    const float* Wk  = (const float*)d_in[3];
    const float* bk  = (const float*)d_in[4];
    const float* Wv  = (const float*)d_in[5];
    const float* bv  = (const float*)d_in[6];
    const float* Wo  = (const float*)d_in[7];
    const float* bo  = (const float*)d_in[8];
    const float* Ws1 = (const float*)d_in[9];
    const float* bs1 = (const float*)d_in[10];
    const float* Ws2 = (const float*)d_in[11];
    float* out = (float*)d_out;

    const size_t MSD = (size_t)Bb * Ss * Dd;   // 4,194,304
    const int M = Bb * Ss;                     // 4096

    char* p = (char*)d_ws;
    __bf16* qb  = (__bf16*)p; p += MSD * sizeof(__bf16);
    __bf16* kb  = (__bf16*)p; p += MSD * sizeof(__bf16);
    __bf16* vb  = (__bf16*)p; p += MSD * sizeof(__bf16);
    __bf16* att = (__bf16*)p; p += MSD * sizeof(__bf16);
    __bf16* xb  = (__bf16*)p; p += MSD * sizeof(__bf16);
    __bf16* xlo = (__bf16*)p; p += MSD * sizeof(__bf16);
    __bf16* WqT = (__bf16*)p; p += (size_t)Dd * Dd * sizeof(__bf16);
    __bf16* WkT = (__bf16*)p; p += (size_t)Dd * Dd * sizeof(__bf16);
    __bf16* WvT = (__bf16*)p; p += (size_t)Dd * Dd * sizeof(__bf16);
    __bf16* WoT = (__bf16*)p; p += (size_t)Dd * Dd * sizeof(__bf16);
    __bf16* W1Th = (__bf16*)p; p += (size_t)512 * Dd * sizeof(__bf16);
    __bf16* W1Tl = (__bf16*)p; p += (size_t)512 * Dd * sizeof(__bf16);
    float* imp  = (float*)p; p += (size_t)Bb * Ss * sizeof(float);
    int* sel_idx = (int*)p; p += (size_t)Bb * Kk * sizeof(int);
    float* oacc = (float*)p; p += (size_t)Bb * Hh * Kk * 64 * sizeof(float);
    float* lsum = (float*)p; p += (size_t)Bb * Hh * Kk * sizeof(float);
    unsigned* macc = (unsigned*)p; p += (size_t)Bb * Hh * Kk * sizeof(unsigned);
    float* Sbuf = (float*)xlo;   // alias: xlo dead after gemm_hilo; 4 MB < 8 MB

    // 1) Pack inputs (+ zero-init accumulators); weights -> transposed bf16.
    pack_x_hilo<<<dim3((int)(MSD / 4 / 256)), 256, 0, stream>>>(
        x, xb, xlo, imp, oacc, lsum, macc);
    transpose_pack<<<dim3(32, 32, 4), 256, 0, stream>>>(Wq, Wk, Wv, Wo, WqT, WkT, WvT, WoT);
    transpose_pack_hilo<<<dim3(16, 32), 256, 0, stream>>>(Ws1, W1Th, W1Tl);
    // 2) Indexer: split-precision MFMA with fused relu*Ws2 atomic epilogue.
    gemm_hilo<<<dim3(8, 32), 256, 0, stream>>>(xb, xlo, W1Th, W1Tl, bs1, Ws2, imp, M, 512, Dd);
    topk_kernel<<<dim3(Bb), 256, 0, stream>>>(imp, sel_idx);
    // 3) QKV projections, bf16 MFMA, bf16 outputs.
    gemm_bf16<__bf16><<<dim3(8, 32, 3), 256, 0, stream>>>(
        xb, WqT, WkT, WvT, bq, bk, bv, qb, kb, vb, M, Dd, Dd);
    // 4) Attention: sparse writes all rows; dense pipeline overwrites the 16
    //    selected rows via split-S 3-phase (scores+max / exp+PV / normalize).
    attn_sparse<<<dim3(Ss / 16, Hh, Bb), 256, 0, stream>>>(qb, kb, vb, sel_idx, att);
    attn_dense_qk<<<dim3(Ss / 128, Hh, Bb), 256, 0, stream>>>(qb, kb, sel_idx, Sbuf, macc);
    attn_dense_pv<<<dim3(Ss / 128, Hh, Bb), 256, 0, stream>>>(vb, Sbuf, macc, lsum, oacc);
    attn_dense_fin<<<dim3(Bb * Hh * Kk), 64, 0, stream>>>(oacc, lsum, sel_idx, att);
    // 5) Output projection, bf16 MFMA, f32 out.
    gemm_bf16<float><<<dim3(8, 32, 1), 256, 0, stream>>>(
        att, WoT, WoT, WoT, bo, bo, bo, out, out, out, M, Dd, Dd);
}

// Round 6
// 267.701 us; speedup vs baseline: 2.9545x; 1.0517x over previous
//
#include <hip/hip_runtime.h>
#include <math.h>

// Problem constants
constexpr int Bb = 2, Ss = 2048, Dd = 1024, Hh = 16, Kk = 16;

typedef __bf16 bf16x8 __attribute__((ext_vector_type(8)));
typedef __bf16 bf16x4 __attribute__((ext_vector_type(4)));
typedef float  f32x4  __attribute__((ext_vector_type(4)));

__device__ __forceinline__ void gld_lds16(const void* g, void* l) {
    __builtin_amdgcn_global_load_lds(
        (const __attribute__((address_space(1))) unsigned int*)g,
        (__attribute__((address_space(3))) unsigned int*)l, 16, 0, 0);
}

// Ordered map for f32 atomicMax on uint (monotone bijection).
__device__ __forceinline__ unsigned fmap(float f) {
    unsigned u = __float_as_uint(f);
    return (u & 0x80000000u) ? ~u : (u | 0x80000000u);
}
__device__ __forceinline__ float funmap(unsigned u) {
    return (u & 0x80000000u) ? __uint_as_float(u ^ 0x80000000u) : __uint_as_float(~u);
}

// ---------------------------------------------------------------------------
// FUSED dispatch: z<3 -> QKV projections (bf16 MFMA, m97 structure, 128x128
// tile); z==3 -> split-precision indexer GEMM (128x64 tile, hi/lo bf16 pair,
// top-k-exact) with fused relu*Ws2 atomicAdd epilogue into imp.
// The two workloads are independent (both read only xb/xlo + weights), so
// co-scheduling hides the indexer's 1-block/CU latency inside QKV's schedule.
// Grid (8, 32, 4), 256 threads, 24 KB LDS carve shared by both paths.
// ---------------------------------------------------------------------------
__global__ void __launch_bounds__(256) gemm_qkv_ind(
    const __bf16* __restrict__ xb, const __bf16* __restrict__ xlo,
    const __bf16* __restrict__ WqT, const __bf16* __restrict__ WkT,
    const __bf16* __restrict__ WvT,
    const float* __restrict__ bq, const float* __restrict__ bk,
    const float* __restrict__ bv,
    __bf16* __restrict__ qb, __bf16* __restrict__ kb, __bf16* __restrict__ vb,
    const __bf16* __restrict__ W1Th, const __bf16* __restrict__ W1Tl,
    const float* __restrict__ bs1, const float* __restrict__ Ws2,
    float* __restrict__ imp)
{
    __shared__ __bf16 sm[12288];   // 24 KB

    const int t    = threadIdx.x;
    const int wave = t >> 6;
    const int lane = t & 63;
    const int bm   = blockIdx.y * 128;
    const int fr   = lane & 15;
    const int fq   = lane >> 4;
    const int K    = Dd;           // 1024
    const int z    = blockIdx.z;

    if (z < 3) {
        // ---------------- QKV path: C = xb @ WT^T + bias, N=1024 ----------
        const __bf16* BT  = (z == 0) ? WqT : (z == 1) ? WkT : WvT;
        const float* bias = (z == 0) ? bq  : (z == 1) ? bk  : bv;
        __bf16*      C    = (z == 0) ? qb  : (z == 1) ? kb  : vb;
        __bf16* As = sm;
        __bf16* Bs = sm + 4096;

        const int bn = blockIdx.x * 128;
        const int wm = (wave & 1) * 64;
        const int wn = (wave >> 1) * 64;

        f32x4 acc[4][4] = {};

        for (int k0 = 0; k0 < K; k0 += 32) {
            #pragma unroll
            for (int l = 0; l < 2; ++l) {
                int c = l * 256 + t;
                const __bf16* ga = xb + (size_t)(bm + (c >> 2)) * K + k0 + (c & 3) * 8;
                gld_lds16(ga, As + (size_t)(l * 256 + wave * 64) * 8);
                const __bf16* gb = BT + (size_t)(bn + (c >> 2)) * K + k0 + (c & 3) * 8;
                gld_lds16(gb, Bs + (size_t)(l * 256 + wave * 64) * 8);
            }
            __syncthreads();

            bf16x8 af[4], bf[4];
            #pragma unroll
            for (int i = 0; i < 4; ++i)
                af[i] = *(const bf16x8*)(As + (wm + i * 16 + fr) * 32 + fq * 8);
            #pragma unroll
            for (int j = 0; j < 4; ++j)
                bf[j] = *(const bf16x8*)(Bs + (wn + j * 16 + fr) * 32 + fq * 8);
            #pragma unroll
            for (int i = 0; i < 4; ++i)
                #pragma unroll
                for (int j = 0; j < 4; ++j)
                    acc[i][j] = __builtin_amdgcn_mfma_f32_16x16x32_bf16(af[i], bf[j], acc[i][j], 0, 0, 0);
            __syncthreads();
        }

        const int cr = (lane >> 4) * 4;
        const int cc = lane & 15;
        #pragma unroll
        for (int j = 0; j < 4; ++j) {
            int col = bn + wn + j * 16 + cc;
            float bb = bias[col];
            #pragma unroll
            for (int i = 0; i < 4; ++i) {
                #pragma unroll
                for (int r = 0; r < 4; ++r)
                    C[(size_t)(bm + wm + i * 16 + cr + r) * Dd + col] =
                        (__bf16)(acc[i][j][r] + bb);
            }
        }
    } else {
        // ---------------- Indexer path: split-precision hi/lo, N=512 ------
        // h = x_hi@W_hi + x_hi@W_lo + x_lo@W_hi + bs1; imp += relu(h)*Ws2.
        // Dropped lo*lo term ~2^-17 rel => logit err ~1e-6 << rank gap: exact.
        __bf16* Ah = sm;
        __bf16* Al = sm + 4096;
        __bf16* Bh = sm + 8192;
        __bf16* Bl = sm + 10240;

        const int bn = blockIdx.x * 64;
        const int wm = (wave & 1) * 64;
        const int wn = (wave >> 1) * 32;

        f32x4 acc[4][2] = {};

        for (int k0 = 0; k0 < K; k0 += 32) {
            #pragma unroll
            for (int l = 0; l < 2; ++l) {
                int c = l * 256 + t;
                size_t goff = (size_t)(bm + (c >> 2)) * K + k0 + (c & 3) * 8;
                gld_lds16(xb  + goff, Ah + (size_t)(l * 256 + wave * 64) * 8);
                gld_lds16(xlo + goff, Al + (size_t)(l * 256 + wave * 64) * 8);
            }
            {
                int c = t;
                size_t goff = (size_t)(bn + (c >> 2)) * K + k0 + (c & 3) * 8;
                gld_lds16(W1Th + goff, Bh + (size_t)(wave * 64) * 8);
                gld_lds16(W1Tl + goff, Bl + (size_t)(wave * 64) * 8);
            }
            __syncthreads();

            bf16x8 ah[4], al[4], bh[2], bl[2];
            #pragma unroll
            for (int i = 0; i < 4; ++i) {
                ah[i] = *(const bf16x8*)(Ah + (wm + i * 16 + fr) * 32 + fq * 8);
                al[i] = *(const bf16x8*)(Al + (wm + i * 16 + fr) * 32 + fq * 8);
            }
            #pragma unroll
            for (int j = 0; j < 2; ++j) {
                bh[j] = *(const bf16x8*)(Bh + (wn + j * 16 + fr) * 32 + fq * 8);
                bl[j] = *(const bf16x8*)(Bl + (wn + j * 16 + fr) * 32 + fq * 8);
            }
            #pragma unroll
            for (int i = 0; i < 4; ++i)
                #pragma unroll
                for (int j = 0; j < 2; ++j) {
                    acc[i][j] = __builtin_amdgcn_mfma_f32_16x16x32_bf16(al[i], bh[j], acc[i][j], 0, 0, 0);
                    acc[i][j] = __builtin_amdgcn_mfma_f32_16x16x32_bf16(ah[i], bl[j], acc[i][j], 0, 0, 0);
                    acc[i][j] = __builtin_amdgcn_mfma_f32_16x16x32_bf16(ah[i], bh[j], acc[i][j], 0, 0, 0);
                }
            __syncthreads();
        }

        const int cr = (lane >> 4) * 4;
        const int cc = lane & 15;
        float bb[2], w2[2];
        #pragma unroll
        for (int j = 0; j < 2; ++j) {
            int col = bn + wn + j * 16 + cc;
            bb[j] = bs1[col];
            w2[j] = Ws2[col];
        }
        #pragma unroll
        for (int i = 0; i < 4; ++i) {
            #pragma unroll
            for (int r = 0; r < 4; ++r) {
                float vsum = fmaxf(acc[i][0][r] + bb[0], 0.f) * w2[0]
                           + fmaxf(acc[i][1][r] + bb[1], 0.f) * w2[1];
                #pragma unroll
                for (int off = 8; off > 0; off >>= 1)
                    vsum += __shfl_xor(vsum, off, 16);
                if (cc == 0)
                    atomicAdd(imp + (bm + wm + i * 16 + cr + r), vsum);
            }
        }
    }
}

// ---------------------------------------------------------------------------
// Out-projection GEMM (m97 structure): out = att @ WoT^T + bo, f32 out.
// ---------------------------------------------------------------------------
__global__ void __launch_bounds__(256) gemm_out(
    const __bf16* __restrict__ A, const __bf16* __restrict__ BT,
    const float* __restrict__ bias, float* __restrict__ C, int M, int N, int K)
{
    __shared__ __bf16 As[128 * 32];
    __shared__ __bf16 Bs[128 * 32];

    const int t    = threadIdx.x;
    const int wave = t >> 6;
    const int lane = t & 63;
    const int bm   = blockIdx.y * 128;
    const int bn   = blockIdx.x * 128;
    const int wm   = (wave & 1) * 64;
    const int wn   = (wave >> 1) * 64;
    const int fr   = lane & 15;
    const int fq   = lane >> 4;

    f32x4 acc[4][4] = {};

    for (int k0 = 0; k0 < K; k0 += 32) {
        #pragma unroll
        for (int l = 0; l < 2; ++l) {
            int c = l * 256 + t;
            const __bf16* ga = A + (size_t)(bm + (c >> 2)) * K + k0 + (c & 3) * 8;
            gld_lds16(ga, As + (size_t)(l * 256 + wave * 64) * 8);
            const __bf16* gb = BT + (size_t)(bn + (c >> 2)) * K + k0 + (c & 3) * 8;
            gld_lds16(gb, Bs + (size_t)(l * 256 + wave * 64) * 8);
        }
        __syncthreads();

        bf16x8 af[4], bf[4];
        #pragma unroll
        for (int i = 0; i < 4; ++i)
            af[i] = *(const bf16x8*)(As + (wm + i * 16 + fr) * 32 + fq * 8);
        #pragma unroll
        for (int j = 0; j < 4; ++j)
            bf[j] = *(const bf16x8*)(Bs + (wn + j * 16 + fr) * 32 + fq * 8);
        #pragma unroll
        for (int i = 0; i < 4; ++i)
            #pragma unroll
            for (int j = 0; j < 4; ++j)
                acc[i][j] = __builtin_amdgcn_mfma_f32_16x16x32_bf16(af[i], bf[j], acc[i][j], 0, 0, 0);
        __syncthreads();
    }

    const int cr = (lane >> 4) * 4;
    const int cc = lane & 15;
    #pragma unroll
    for (int j = 0; j < 4; ++j) {
        int col = bn + wn + j * 16 + cc;
        float bb = bias[col];
        #pragma unroll
        for (int i = 0; i < 4; ++i) {
            #pragma unroll
            for (int r = 0; r < 4; ++r)
                C[(size_t)(bm + wm + i * 16 + cr + r) * N + col] = acc[i][j][r] + bb;
        }
    }
}

// ---------------------------------------------------------------------------
// Pack x (f32 -> bf16 hi + lo residual). Also zero-inits imp and the dense-
// attention accumulators.
// ---------------------------------------------------------------------------
__global__ void __launch_bounds__(256) pack_x_hilo(
    const float* __restrict__ src, __bf16* __restrict__ hi, __bf16* __restrict__ lo,
    float* __restrict__ imp, float* __restrict__ oacc,
    float* __restrict__ lsum, unsigned* __restrict__ macc)
{
    int i = blockIdx.x * 256 + threadIdx.x;
    if (i < Bb * Ss) imp[i] = 0.f;
    if (i < Bb * Hh * Kk * 64) oacc[i] = 0.f;
    if (i < Bb * Hh * Kk) { lsum[i] = 0.f; macc[i] = 0u; }
    float4 v = ((const float4*)src)[i];
    bf16x4 h = { (__bf16)v.x, (__bf16)v.y, (__bf16)v.z, (__bf16)v.w };
    bf16x4 l = { (__bf16)(v.x - (float)h[0]), (__bf16)(v.y - (float)h[1]),
                 (__bf16)(v.z - (float)h[2]), (__bf16)(v.w - (float)h[3]) };
    ((bf16x4*)hi)[i] = h;
    ((bf16x4*)lo)[i] = l;
}

// ---------------------------------------------------------------------------
// Transpose + pack all weights in one dispatch. z<4: square 1024x1024 W ->
// bf16 WT. z==4: Ws1 [1024,512] -> hi/lo bf16 pair (blockIdx.x<16 active).
// ---------------------------------------------------------------------------
__global__ void __launch_bounds__(256) transpose_all(
    const float* __restrict__ W0, const float* __restrict__ W1,
    const float* __restrict__ W2, const float* __restrict__ W3,
    __bf16* __restrict__ T0, __bf16* __restrict__ T1,
    __bf16* __restrict__ T2, __bf16* __restrict__ T3,
    const float* __restrict__ Ws1, __bf16* __restrict__ Th, __bf16* __restrict__ Tl)
{
    __shared__ float tile[32][33];
    int tx = threadIdx.x & 31, ty = threadIdx.x >> 5;
    int n0 = blockIdx.x * 32, k0 = blockIdx.y * 32;
    int z = blockIdx.z;

    if (z < 4) {
        const float* W = (z == 0) ? W0 : (z == 1) ? W1 : (z == 2) ? W2 : W3;
        __bf16*      T = (z == 0) ? T0 : (z == 1) ? T1 : (z == 2) ? T2 : T3;
        #pragma unroll
        for (int i = 0; i < 32; i += 8)
            tile[ty + i][tx] = W[(size_t)(k0 + ty + i) * 1024 + n0 + tx];
        __syncthreads();
        #pragma unroll
        for (int i = 0; i < 32; i += 8)
            T[(size_t)(n0 + ty + i) * 1024 + k0 + tx] = (__bf16)tile[tx][ty + i];
    } else {
        if (blockIdx.x >= 16) return;
        #pragma unroll
        for (int i = 0; i < 32; i += 8)
            tile[ty + i][tx] = Ws1[(size_t)(k0 + ty + i) * 512 + n0 + tx];
        __syncthreads();
        #pragma unroll
        for (int i = 0; i < 32; i += 8) {
            float v = tile[tx][ty + i];
            __bf16 h = (__bf16)v;
            Th[(size_t)(n0 + ty + i) * 1024 + k0 + tx] = h;
            Tl[(size_t)(n0 + ty + i) * 1024 + k0 + tx] = (__bf16)(v - (float)h);
        }
    }
}

// ---------------------------------------------------------------------------
// Exact top-K per batch via K iterative argmax passes.
// ---------------------------------------------------------------------------
__global__ void __launch_bounds__(256) topk_kernel(
    const float* __restrict__ imp, int* __restrict__ sel_idx)
{
    int b = blockIdx.x;
    int t = threadIdx.x;
    __shared__ float vals[Ss];
    __shared__ float sv[256];
    __shared__ int   si[256];

    for (int j = t; j < Ss; j += 256) vals[j] = imp[b * Ss + j];
    __syncthreads();

    for (int it = 0; it < Kk; ++it) {
        float best = -1e30f; int bidx = 0x7fffffff;
        for (int j = t; j < Ss; j += 256) {
            float v = vals[j];
            if (v > best || (v == best && j < bidx)) { best = v; bidx = j; }
        }
        sv[t] = best; si[t] = bidx;
        __syncthreads();
        for (int off = 128; off > 0; off >>= 1) {
            if (t < off) {
                float ov = sv[t + off]; int oi = si[t + off];
                if (ov > sv[t] || (ov == sv[t] && oi < si[t])) { sv[t] = ov; si[t] = oi; }
            }
            __syncthreads();
        }
        if (t == 0) {
            sel_idx[b * Kk + it] = si[0];
            vals[si[0]] = -1e30f;
        }
        __syncthreads();
    }
}

// ---------------------------------------------------------------------------
// Sparse attention: ALL rows attend over the 16 selected keys (selected rows
// overwritten by dense pipeline). One block per (b, h, 16 queries).
// ---------------------------------------------------------------------------
__global__ void __launch_bounds__(256) attn_sparse(
    const __bf16* __restrict__ q, const __bf16* __restrict__ k,
    const __bf16* __restrict__ v, const int* __restrict__ sel_idx,
    __bf16* __restrict__ att)
{
    const int b  = blockIdx.z;
    const int h  = blockIdx.y;
    const int q0 = blockIdx.x * 16;
    const int t  = threadIdx.x;

    __shared__ float KT[64][17];
    __shared__ float Vs[16][64];
    __shared__ float qsh[16][65];
    __shared__ float wsh[16][16];
    __shared__ int   sj[16];

    if (t < 16) sj[t] = sel_idx[b * Kk + t];
    __syncthreads();

    {
        int row = t >> 4, d0 = (t & 15) * 4;
        bf16x4 kv = *(const bf16x4*)(k + ((size_t)(b * Ss + sj[row])) * Dd + h * 64 + d0);
        bf16x4 vv = *(const bf16x4*)(v + ((size_t)(b * Ss + sj[row])) * Dd + h * 64 + d0);
        bf16x4 qv = *(const bf16x4*)(q + ((size_t)(b * Ss + q0 + row)) * Dd + h * 64 + d0);
        #pragma unroll
        for (int i = 0; i < 4; ++i) {
            KT[d0 + i][row]  = (float)kv[i];
            Vs[row][d0 + i]  = (float)vv[i];
            qsh[row][d0 + i] = (float)qv[i];
        }
    }
    __syncthreads();

    const int wave = t >> 6, lane = t & 63;
    const int ql = lane >> 4, j = lane & 15;
    const int qi = wave * 4 + ql;

    float s = 0.f;
    #pragma unroll
    for (int d = 0; d < 64; ++d) s = fmaf(qsh[qi][d], KT[d][j], s);
    s *= 0.125f;

    float m = s;
    #pragma unroll
    for (int off = 8; off > 0; off >>= 1) m = fmaxf(m, __shfl_xor(m, off, 16));
    float e = __expf(s - m);
    float sum = e;
    #pragma unroll
    for (int off = 8; off > 0; off >>= 1) sum += __shfl_xor(sum, off, 16);
    wsh[qi][j] = e / sum;

    #pragma unroll
    for (int q2 = 0; q2 < 4; ++q2) {
        int qq = wave * 4 + q2;
        float o = 0.f;
        #pragma unroll
        for (int jj = 0; jj < 16; ++jj)
            o = fmaf(wsh[qq][jj], Vs[jj][lane], o);
        att[((size_t)(b * Ss + q0 + qq)) * Dd + h * 64 + lane] = (__bf16)o;
    }
}

// ---------------------------------------------------------------------------
// Dense attention phase 1: scores for 16 selected queries x 128-key chunk.
// ---------------------------------------------------------------------------
__global__ void __launch_bounds__(256) attn_dense_qk(
    const __bf16* __restrict__ q, const __bf16* __restrict__ k,
    const int* __restrict__ sel_idx, float* __restrict__ Sbuf,
    unsigned* __restrict__ macc)
{
    const int b  = blockIdx.z, h = blockIdx.y, j0 = blockIdx.x * 128;
    const int t  = threadIdx.x;

    __shared__ float Ks[128][65];
    __shared__ float Qs[16][65];

    #pragma unroll
    for (int l = 0; l < 4; ++l) {
        int c = t + 256 * l;
        int row = c >> 3, seg = c & 7;
        bf16x8 kv = *(const bf16x8*)(k + ((size_t)(b * Ss + j0 + row)) * Dd + h * 64 + seg * 8);
        #pragma unroll
        for (int e = 0; e < 8; ++e) Ks[row][seg * 8 + e] = (float)kv[e];
    }
    if (t < 128) {
        int row = t >> 3, seg = t & 7;
        int i = sel_idx[b * Kk + row];
        bf16x8 qv = *(const bf16x8*)(q + ((size_t)(b * Ss + i)) * Dd + h * 64 + seg * 8);
        #pragma unroll
        for (int e = 0; e < 8; ++e) Qs[row][seg * 8 + e] = (float)qv[e];
    }
    __syncthreads();

    const int qi = t >> 4, ks = t & 15;
    const int bhq = (b * Hh + h) * Kk + qi;
    float lmax = -1e30f;
    #pragma unroll
    for (int s8 = 0; s8 < 8; ++s8) {
        int j = ks + s8 * 16;
        float s = 0.f;
        #pragma unroll
        for (int d = 0; d < 64; ++d) s = fmaf(Qs[qi][d], Ks[j][d], s);
        s *= 0.125f;
        Sbuf[(size_t)bhq * Ss + j0 + j] = s;
        lmax = fmaxf(lmax, s);
    }
    #pragma unroll
    for (int off = 8; off > 0; off >>= 1) lmax = fmaxf(lmax, __shfl_xor(lmax, off, 16));
    if (ks == 0) atomicMax(macc + bhq, fmap(lmax));
}

// ---------------------------------------------------------------------------
// Dense attention phase 2: e = exp(s - m); partial sums + partial PV atomics.
// ---------------------------------------------------------------------------
__global__ void __launch_bounds__(256) attn_dense_pv(
    const __bf16* __restrict__ v, const float* __restrict__ Sbuf,
    const unsigned* __restrict__ macc, float* __restrict__ lsum,
    float* __restrict__ oacc)
{
    const int b  = blockIdx.z, h = blockIdx.y, j0 = blockIdx.x * 128;
    const int t  = threadIdx.x;

    __shared__ float Vs[128][64];
    __shared__ float Es[16][144];

    #pragma unroll
    for (int l = 0; l < 4; ++l) {
        int c = t + 256 * l;
        int row = c >> 3, seg = c & 7;
        bf16x8 vv = *(const bf16x8*)(v + ((size_t)(b * Ss + j0 + row)) * Dd + h * 64 + seg * 8);
        #pragma unroll
        for (int e = 0; e < 8; ++e) Vs[row][seg * 8 + e] = (float)vv[e];
    }

    const int qi = t >> 4, ks = t & 15;
    const int bhq = (b * Hh + h) * Kk + qi;
    const float mq = funmap(macc[bhq]);
    float psum = 0.f;
    #pragma unroll
    for (int s8 = 0; s8 < 8; ++s8) {
        int j = ks + s8 * 16;
        float e = __expf(Sbuf[(size_t)bhq * Ss + j0 + j] - mq);
        Es[qi][j] = e;
        psum += e;
    }
    #pragma unroll
    for (int off = 8; off > 0; off >>= 1) psum += __shfl_xor(psum, off, 16);
    if (ks == 0) atomicAdd(lsum + bhq, psum);
    __syncthreads();

    const int d = t & 63, qg = t >> 6;
    #pragma unroll
    for (int qq = 0; qq < 4; ++qq) {
        int qx = qg * 4 + qq;
        float o = 0.f;
        #pragma unroll 4
        for (int jj = 0; jj < 128; ++jj)
            o = fmaf(Es[qx][jj], Vs[jj][d], o);
        atomicAdd(oacc + (size_t)((b * Hh + h) * Kk + qx) * 64 + d, o);
    }
}

// ---------------------------------------------------------------------------
// Dense attention phase 3: att[selected rows] = oacc / lsum.
// ---------------------------------------------------------------------------
__global__ void __launch_bounds__(64) attn_dense_fin(
    const float* __restrict__ oacc, const float* __restrict__ lsum,
    const int* __restrict__ sel_idx, __bf16* __restrict__ att)
{
    int bid = blockIdx.x;
    int qi = bid & 15, h = (bid >> 4) & 15, b = bid >> 8;
    int bhq = (b * Hh + h) * Kk + qi;
    int i = sel_idx[b * Kk + qi];
    float val = oacc[(size_t)bhq * 64 + threadIdx.x] / lsum[bhq];
    att[((size_t)(b * Ss + i)) * Dd + h * 64 + threadIdx.x] = (__bf16)val;
}

// ---------------------------------------------------------------------------
extern "C" void kernel_launch(void* const* d_in, const int* in_sizes, int n_in,
                              void* d_out, int out_size, void* d_ws, size_t ws_size,
                              hipStream_t stream)
{
    const float* x   = (const float*)d_in[0];
    const float* Wq  = (const float*)d_in[1];
    const float* bq  = (const float*)d_in[2];
    const float* Wk  = (const float*)d_in[3];
    const float* bk  = (const float*)d_in[4];
    const float* Wv  = (const float*)d_in[5];
    const float* bv  = (const float*)d_in[6];
    const float* Wo  = (const float*)d_in[7];
    const float* bo  = (const float*)d_in[8];
    const float* Ws1 = (const float*)d_in[9];
    const float* bs1 = (const float*)d_in[10];
    const float* Ws2 = (const float*)d_in[11];
    float* out = (float*)d_out;

    const size_t MSD = (size_t)Bb * Ss * Dd;   // 4,194,304
    const int M = Bb * Ss;                     // 4096

    char* p = (char*)d_ws;
    __bf16* qb  = (__bf16*)p; p += MSD * sizeof(__bf16);
    __bf16* kb  = (__bf16*)p; p += MSD * sizeof(__bf16);
    __bf16* vb  = (__bf16*)p; p += MSD * sizeof(__bf16);
    __bf16* att = (__bf16*)p; p += MSD * sizeof(__bf16);
    __bf16* xb  = (__bf16*)p; p += MSD * sizeof(__bf16);
    __bf16* xlo = (__bf16*)p; p += MSD * sizeof(__bf16);
    __bf16* WqT = (__bf16*)p; p += (size_t)Dd * Dd * sizeof(__bf16);
    __bf16* WkT = (__bf16*)p; p += (size_t)Dd * Dd * sizeof(__bf16);
    __bf16* WvT = (__bf16*)p; p += (size_t)Dd * Dd * sizeof(__bf16);
    __bf16* WoT = (__bf16*)p; p += (size_t)Dd * Dd * sizeof(__bf16);
    __bf16* W1Th = (__bf16*)p; p += (size_t)512 * Dd * sizeof(__bf16);
    __bf16* W1Tl = (__bf16*)p; p += (size_t)512 * Dd * sizeof(__bf16);
    float* imp  = (float*)p; p += (size_t)Bb * Ss * sizeof(float);
    int* sel_idx = (int*)p; p += (size_t)Bb * Kk * sizeof(int);
    float* oacc = (float*)p; p += (size_t)Bb * Hh * Kk * 64 * sizeof(float);
    float* lsum = (float*)p; p += (size_t)Bb * Hh * Kk * sizeof(float);
    unsigned* macc = (unsigned*)p; p += (size_t)Bb * Hh * Kk * sizeof(unsigned);
    float* Sbuf = (float*)xlo;   // alias: xlo dead after gemm_qkv_ind

    // 1) Pack x -> bf16 hi/lo (+ zero accumulators); all weights transposed.
    pack_x_hilo<<<dim3((int)(MSD / 4 / 256)), 256, 0, stream>>>(
        x, xb, xlo, imp, oacc, lsum, macc);
    transpose_all<<<dim3(32, 32, 5), 256, 0, stream>>>(
        Wq, Wk, Wv, Wo, WqT, WkT, WvT, WoT, Ws1, W1Th, W1Tl);
    // 2) FUSED: QKV projections (z<3) + split-precision indexer (z==3).
    gemm_qkv_ind<<<dim3(8, 32, 4), 256, 0, stream>>>(
        xb, xlo, WqT, WkT, WvT, bq, bk, bv, qb, kb, vb,
        W1Th, W1Tl, bs1, Ws2, imp);
    // 3) Exact top-K selection.
    topk_kernel<<<dim3(Bb), 256, 0, stream>>>(imp, sel_idx);
    // 4) Attention: sparse writes all rows; dense pipeline overwrites the 16
    //    selected rows via split-S 3-phase.
    attn_sparse<<<dim3(Ss / 16, Hh, Bb), 256, 0, stream>>>(qb, kb, vb, sel_idx, att);
    attn_dense_qk<<<dim3(Ss / 128, Hh, Bb), 256, 0, stream>>>(qb, kb, sel_idx, Sbuf, macc);
    attn_dense_pv<<<dim3(Ss / 128, Hh, Bb), 256, 0, stream>>>(vb, Sbuf, macc, lsum, oacc);
    attn_dense_fin<<<dim3(Bb * Hh * Kk), 64, 0, stream>>>(oacc, lsum, sel_idx, att);
    // 5) Output projection, bf16 MFMA, f32 out.
    gemm_out<<<dim3(8, 32), 256, 0, stream>>>(att, WoT, bo, out, M, Dd, Dd);
}

// Round 7
// 260.755 us; speedup vs baseline: 3.0332x; 1.0266x over previous
//
#include <hip/hip_runtime.h>
#include <math.h>

// Problem constants
constexpr int Bb = 2, Ss = 2048, Dd = 1024, Hh = 16, Kk = 16;

typedef __bf16 bf16x8 __attribute__((ext_vector_type(8)));
typedef __bf16 bf16x4 __attribute__((ext_vector_type(4)));
typedef float  f32x4  __attribute__((ext_vector_type(4)));

__device__ __forceinline__ void gld_lds16(const void* g, void* l) {
    __builtin_amdgcn_global_load_lds(
        (const __attribute__((address_space(1))) unsigned int*)g,
        (__attribute__((address_space(3))) unsigned int*)l, 16, 0, 0);
}

// Ordered map for f32 atomicMax on uint (monotone bijection).
__device__ __forceinline__ unsigned fmap(float f) {
    unsigned u = __float_as_uint(f);
    return (u & 0x80000000u) ? ~u : (u | 0x80000000u);
}
__device__ __forceinline__ float funmap(unsigned u) {
    return (u & 0x80000000u) ? __uint_as_float(u ^ 0x80000000u) : __uint_as_float(~u);
}

// ---------------------------------------------------------------------------
// FUSED dispatch, 1D grid of 1024 blocks, z = bid&3 interleaved so indexer
// blocks co-schedule with QKV blocks from dispatch start.
//  z<3 : QKV projection (bf16 MFMA, 128x128 tile, BK=64 -> 16 barriers).
//  z==3: split-precision indexer GEMM (128x64 tile, BK=32, hi/lo bf16 pair,
//        top-k-exact) + fused relu*Ws2 atomicAdd epilogue into imp.
// LDS fragment layout XOR-swizzled (seg ^ row) at STAGING-ADDRESS time:
// global_load_lds dest stays lane-linear, but chunk->slot mapping spreads
// ds_read_b128 banks (8-way -> 2-way, free per m136).
// ---------------------------------------------------------------------------
__global__ void __launch_bounds__(256) gemm_qkv_ind(
    const __bf16* __restrict__ xb, const __bf16* __restrict__ xlo,
    const __bf16* __restrict__ WqT, const __bf16* __restrict__ WkT,
    const __bf16* __restrict__ WvT,
    const float* __restrict__ bq, const float* __restrict__ bk,
    const float* __restrict__ bv,
    __bf16* __restrict__ qb, __bf16* __restrict__ kb, __bf16* __restrict__ vb,
    const __bf16* __restrict__ W1Th, const __bf16* __restrict__ W1Tl,
    const float* __restrict__ bs1, const float* __restrict__ Ws2,
    float* __restrict__ imp)
{
    __shared__ __bf16 sm[16384];   // 32 KB

    const int bid  = blockIdx.x;
    const int z    = bid & 3;
    const int rid  = bid >> 2;      // 0..255
    const int bxi  = rid & 7;
    const int bm   = (rid >> 3) * 128;
    const int t    = threadIdx.x;
    const int wave = t >> 6;
    const int lane = t & 63;
    const int fr   = lane & 15;
    const int fq   = lane >> 4;
    const int K    = Dd;            // 1024

    if (z < 3) {
        // ---------------- QKV path: C = xb @ WT^T + bias, BK=64 -----------
        const __bf16* BT  = (z == 0) ? WqT : (z == 1) ? WkT : WvT;
        const float* bias = (z == 0) ? bq  : (z == 1) ? bk  : bv;
        __bf16*      C    = (z == 0) ? qb  : (z == 1) ? kb  : vb;
        __bf16* As = sm;            // 128 x 64, swizzled rows of 8 chunks
        __bf16* Bs = sm + 8192;

        const int bn = bxi * 128;
        const int wm = (wave & 1) * 64;
        const int wn = (wave >> 1) * 64;

        f32x4 acc[4][4] = {};

        for (int k0 = 0; k0 < K; k0 += 64) {
            #pragma unroll
            for (int l = 0; l < 4; ++l) {
                int c = l * 256 + t;                 // dest chunk 0..1023
                int row = c >> 3, seg = (c & 7) ^ (row & 7);
                gld_lds16(xb + (size_t)(bm + row) * K + k0 + seg * 8,
                          As + (size_t)(l * 256 + wave * 64) * 8);
                gld_lds16(BT + (size_t)(bn + row) * K + k0 + seg * 8,
                          Bs + (size_t)(l * 256 + wave * 64) * 8);
            }
            __syncthreads();

            #pragma unroll
            for (int s = 0; s < 2; ++s) {
                bf16x8 af[4], bf[4];
                #pragma unroll
                for (int i = 0; i < 4; ++i) {
                    int row = wm + i * 16 + fr;
                    af[i] = *(const bf16x8*)(As + row * 64 + (((s * 4 + fq) ^ (row & 7)) * 8));
                }
                #pragma unroll
                for (int j = 0; j < 4; ++j) {
                    int row = wn + j * 16 + fr;
                    bf[j] = *(const bf16x8*)(Bs + row * 64 + (((s * 4 + fq) ^ (row & 7)) * 8));
                }
                #pragma unroll
                for (int i = 0; i < 4; ++i)
                    #pragma unroll
                    for (int j = 0; j < 4; ++j)
                        acc[i][j] = __builtin_amdgcn_mfma_f32_16x16x32_bf16(af[i], bf[j], acc[i][j], 0, 0, 0);
            }
            __syncthreads();
        }

        const int cr = (lane >> 4) * 4;
        const int cc = lane & 15;
        #pragma unroll
        for (int j = 0; j < 4; ++j) {
            int col = bn + wn + j * 16 + cc;
            float bb = bias[col];
            #pragma unroll
            for (int i = 0; i < 4; ++i) {
                #pragma unroll
                for (int r = 0; r < 4; ++r)
                    C[(size_t)(bm + wm + i * 16 + cr + r) * Dd + col] =
                        (__bf16)(acc[i][j][r] + bb);
            }
        }
    } else {
        // ---------------- Indexer path: hi/lo split, BK=32, N=512 ---------
        // h = x_hi@W_hi + x_hi@W_lo + x_lo@W_hi + bs1; imp += relu(h)*Ws2.
        // Dropped lo*lo term ~2^-17 rel => logit err ~1e-6 << rank gap.
        __bf16* Ah = sm;            // 128x32
        __bf16* Al = sm + 4096;
        __bf16* Bh = sm + 8192;     // 64x32
        __bf16* Bl = sm + 10240;

        const int bn = bxi * 64;
        const int wm = (wave & 1) * 64;
        const int wn = (wave >> 1) * 32;

        f32x4 acc[4][2] = {};

        for (int k0 = 0; k0 < K; k0 += 32) {
            #pragma unroll
            for (int l = 0; l < 2; ++l) {
                int c = l * 256 + t;                 // A chunks 0..511
                int row = c >> 2, seg = (c & 3) ^ (row & 3);
                size_t goff = (size_t)(bm + row) * K + k0 + seg * 8;
                gld_lds16(xb  + goff, Ah + (size_t)(l * 256 + wave * 64) * 8);
                gld_lds16(xlo + goff, Al + (size_t)(l * 256 + wave * 64) * 8);
            }
            {
                int c = t;                           // B chunks 0..255
                int row = c >> 2, seg = (c & 3) ^ (row & 3);
                size_t goff = (size_t)(bn + row) * K + k0 + seg * 8;
                gld_lds16(W1Th + goff, Bh + (size_t)(wave * 64) * 8);
                gld_lds16(W1Tl + goff, Bl + (size_t)(wave * 64) * 8);
            }
            __syncthreads();

            bf16x8 ah[4], al[4], bh[2], bl[2];
            #pragma unroll
            for (int i = 0; i < 4; ++i) {
                int row = wm + i * 16 + fr;
                int off = row * 32 + ((fq ^ (row & 3)) * 8);
                ah[i] = *(const bf16x8*)(Ah + off);
                al[i] = *(const bf16x8*)(Al + off);
            }
            #pragma unroll
            for (int j = 0; j < 2; ++j) {
                int row = wn + j * 16 + fr;
                int off = row * 32 + ((fq ^ (row & 3)) * 8);
                bh[j] = *(const bf16x8*)(Bh + off);
                bl[j] = *(const bf16x8*)(Bl + off);
            }
            #pragma unroll
            for (int i = 0; i < 4; ++i)
                #pragma unroll
                for (int j = 0; j < 2; ++j) {
                    acc[i][j] = __builtin_amdgcn_mfma_f32_16x16x32_bf16(al[i], bh[j], acc[i][j], 0, 0, 0);
                    acc[i][j] = __builtin_amdgcn_mfma_f32_16x16x32_bf16(ah[i], bl[j], acc[i][j], 0, 0, 0);
                    acc[i][j] = __builtin_amdgcn_mfma_f32_16x16x32_bf16(ah[i], bh[j], acc[i][j], 0, 0, 0);
                }
            __syncthreads();
        }

        const int cr = (lane >> 4) * 4;
        const int cc = lane & 15;
        float bb[2], w2[2];
        #pragma unroll
        for (int j = 0; j < 2; ++j) {
            int col = bn + wn + j * 16 + cc;
            bb[j] = bs1[col];
            w2[j] = Ws2[col];
        }
        #pragma unroll
        for (int i = 0; i < 4; ++i) {
            #pragma unroll
            for (int r = 0; r < 4; ++r) {
                float vsum = fmaxf(acc[i][0][r] + bb[0], 0.f) * w2[0]
                           + fmaxf(acc[i][1][r] + bb[1], 0.f) * w2[1];
                #pragma unroll
                for (int off = 8; off > 0; off >>= 1)
                    vsum += __shfl_xor(vsum, off, 16);
                if (cc == 0)
                    atomicAdd(imp + (bm + wm + i * 16 + cr + r), vsum);
            }
        }
    }
}

// ---------------------------------------------------------------------------
// Out-projection GEMM: out = att @ WoT^T + bo, f32 out. 64x128 tile, BK=64,
// grid (8, 64) = 512 blocks (2/CU vs the old 1/CU). Swizzled LDS.
// ---------------------------------------------------------------------------
__global__ void __launch_bounds__(256) gemm_out(
    const __bf16* __restrict__ A, const __bf16* __restrict__ BT,
    const float* __restrict__ bias, float* __restrict__ C, int M, int N, int K)
{
    __shared__ __bf16 As[64 * 64];     // 8 KB
    __shared__ __bf16 Bs[128 * 64];    // 16 KB

    const int t    = threadIdx.x;
    const int wave = t >> 6;
    const int lane = t & 63;
    const int bm   = blockIdx.y * 64;
    const int bn   = blockIdx.x * 128;
    const int wm   = (wave & 1) * 32;
    const int wn   = (wave >> 1) * 64;
    const int fr   = lane & 15;
    const int fq   = lane >> 4;

    f32x4 acc[2][4] = {};

    for (int k0 = 0; k0 < K; k0 += 64) {
        #pragma unroll
        for (int l = 0; l < 2; ++l) {            // A: 512 chunks
            int c = l * 256 + t;
            int row = c >> 3, seg = (c & 7) ^ (row & 7);
            gld_lds16(A + (size_t)(bm + row) * K + k0 + seg * 8,
                      As + (size_t)(l * 256 + wave * 64) * 8);
        }
        #pragma unroll
        for (int l = 0; l < 4; ++l) {            // B: 1024 chunks
            int c = l * 256 + t;
            int row = c >> 3, seg = (c & 7) ^ (row & 7);
            gld_lds16(BT + (size_t)(bn + row) * K + k0 + seg * 8,
                      Bs + (size_t)(l * 256 + wave * 64) * 8);
        }
        __syncthreads();

        #pragma unroll
        for (int s = 0; s < 2; ++s) {
            bf16x8 af[2], bf[4];
            #pragma unroll
            for (int i = 0; i < 2; ++i) {
                int row = wm + i * 16 + fr;
                af[i] = *(const bf16x8*)(As + row * 64 + (((s * 4 + fq) ^ (row & 7)) * 8));
            }
            #pragma unroll
            for (int j = 0; j < 4; ++j) {
                int row = wn + j * 16 + fr;
                bf[j] = *(const bf16x8*)(Bs + row * 64 + (((s * 4 + fq) ^ (row & 7)) * 8));
            }
            #pragma unroll
            for (int i = 0; i < 2; ++i)
                #pragma unroll
                for (int j = 0; j < 4; ++j)
                    acc[i][j] = __builtin_amdgcn_mfma_f32_16x16x32_bf16(af[i], bf[j], acc[i][j], 0, 0, 0);
        }
        __syncthreads();
    }

    const int cr = (lane >> 4) * 4;
    const int cc = lane & 15;
    #pragma unroll
    for (int j = 0; j < 4; ++j) {
        int col = bn + wn + j * 16 + cc;
        float bb = bias[col];
        #pragma unroll
        for (int i = 0; i < 2; ++i) {
            #pragma unroll
            for (int r = 0; r < 4; ++r)
                C[(size_t)(bm + wm + i * 16 + cr + r) * N + col] = acc[i][j][r] + bb;
        }
    }
}

// ---------------------------------------------------------------------------
// Merged prep: bid<4096 -> pack x (f32 -> bf16 hi/lo) + zero-init of imp and
// dense-attention accumulators; bid>=4096 -> weight transpose+pack (z<4:
// square 1024x1024 -> bf16 WT; z==4: Ws1 -> hi/lo bf16 pair).
// ---------------------------------------------------------------------------
__global__ void __launch_bounds__(256) prep_kernel(
    const float* __restrict__ x, __bf16* __restrict__ hi, __bf16* __restrict__ lo,
    float* __restrict__ imp, float* __restrict__ oacc,
    float* __restrict__ lsum, unsigned* __restrict__ macc,
    const float* __restrict__ W0, const float* __restrict__ W1,
    const float* __restrict__ W2, const float* __restrict__ W3,
    __bf16* __restrict__ T0, __bf16* __restrict__ T1,
    __bf16* __restrict__ T2, __bf16* __restrict__ T3,
    const float* __restrict__ Ws1, __bf16* __restrict__ Th, __bf16* __restrict__ Tl)
{
    __shared__ float tile[32][33];
    const int bid = blockIdx.x;

    if (bid < 4096) {
        int i = bid * 256 + threadIdx.x;
        if (i < Bb * Ss) imp[i] = 0.f;
        if (i < Bb * Hh * Kk * 64) oacc[i] = 0.f;
        if (i < Bb * Hh * Kk) { lsum[i] = 0.f; macc[i] = 0u; }
        float4 v = ((const float4*)x)[i];
        bf16x4 h = { (__bf16)v.x, (__bf16)v.y, (__bf16)v.z, (__bf16)v.w };
        bf16x4 l = { (__bf16)(v.x - (float)h[0]), (__bf16)(v.y - (float)h[1]),
                     (__bf16)(v.z - (float)h[2]), (__bf16)(v.w - (float)h[3]) };
        ((bf16x4*)hi)[i] = h;
        ((bf16x4*)lo)[i] = l;
        return;
    }

    int tid = bid - 4096;
    int z   = tid >> 10;
    int rem = tid & 1023;
    int n0  = (rem & 31) * 32;
    int k0  = (rem >> 5) * 32;
    int tx = threadIdx.x & 31, ty = threadIdx.x >> 5;

    if (z < 4) {
        const float* W = (z == 0) ? W0 : (z == 1) ? W1 : (z == 2) ? W2 : W3;
        __bf16*      T = (z == 0) ? T0 : (z == 1) ? T1 : (z == 2) ? T2 : T3;
        #pragma unroll
        for (int i = 0; i < 32; i += 8)
            tile[ty + i][tx] = W[(size_t)(k0 + ty + i) * 1024 + n0 + tx];
        __syncthreads();
        #pragma unroll
        for (int i = 0; i < 32; i += 8)
            T[(size_t)(n0 + ty + i) * 1024 + k0 + tx] = (__bf16)tile[tx][ty + i];
    } else {
        if (n0 >= 512) return;
        #pragma unroll
        for (int i = 0; i < 32; i += 8)
            tile[ty + i][tx] = Ws1[(size_t)(k0 + ty + i) * 512 + n0 + tx];
        __syncthreads();
        #pragma unroll
        for (int i = 0; i < 32; i += 8) {
            float v = tile[tx][ty + i];
            __bf16 h = (__bf16)v;
            Th[(size_t)(n0 + ty + i) * 1024 + k0 + tx] = h;
            Tl[(size_t)(n0 + ty + i) * 1024 + k0 + tx] = (__bf16)(v - (float)h);
        }
    }
}

// ---------------------------------------------------------------------------
// Exact top-K per batch via K iterative argmax passes.
// ---------------------------------------------------------------------------
__global__ void __launch_bounds__(256) topk_kernel(
    const float* __restrict__ imp, int* __restrict__ sel_idx)
{
    int b = blockIdx.x;
    int t = threadIdx.x;
    __shared__ float vals[Ss];
    __shared__ float sv[256];
    __shared__ int   si[256];

    for (int j = t; j < Ss; j += 256) vals[j] = imp[b * Ss + j];
    __syncthreads();

    for (int it = 0; it < Kk; ++it) {
        float best = -1e30f; int bidx = 0x7fffffff;
        for (int j = t; j < Ss; j += 256) {
            float v = vals[j];
            if (v > best || (v == best && j < bidx)) { best = v; bidx = j; }
        }
        sv[t] = best; si[t] = bidx;
        __syncthreads();
        for (int off = 128; off > 0; off >>= 1) {
            if (t < off) {
                float ov = sv[t + off]; int oi = si[t + off];
                if (ov > sv[t] || (ov == sv[t] && oi < si[t])) { sv[t] = ov; si[t] = oi; }
            }
            __syncthreads();
        }
        if (t == 0) {
            sel_idx[b * Kk + it] = si[0];
            vals[si[0]] = -1e30f;
        }
        __syncthreads();
    }
}

// ---------------------------------------------------------------------------
// Sparse attention: ALL rows attend over the 16 selected keys (selected rows
// overwritten by dense pipeline). One block per (b, h, 16 queries).
// ---------------------------------------------------------------------------
__global__ void __launch_bounds__(256) attn_sparse(
    const __bf16* __restrict__ q, const __bf16* __restrict__ k,
    const __bf16* __restrict__ v, const int* __restrict__ sel_idx,
    __bf16* __restrict__ att)
{
    const int b  = blockIdx.z;
    const int h  = blockIdx.y;
    const int q0 = blockIdx.x * 16;
    const int t  = threadIdx.x;

    __shared__ float KT[64][17];
    __shared__ float Vs[16][64];
    __shared__ float qsh[16][65];
    __shared__ float wsh[16][16];
    __shared__ int   sj[16];

    if (t < 16) sj[t] = sel_idx[b * Kk + t];
    __syncthreads();

    {
        int row = t >> 4, d0 = (t & 15) * 4;
        bf16x4 kv = *(const bf16x4*)(k + ((size_t)(b * Ss + sj[row])) * Dd + h * 64 + d0);
        bf16x4 vv = *(const bf16x4*)(v + ((size_t)(b * Ss + sj[row])) * Dd + h * 64 + d0);
        bf16x4 qv = *(const bf16x4*)(q + ((size_t)(b * Ss + q0 + row)) * Dd + h * 64 + d0);
        #pragma unroll
        for (int i = 0; i < 4; ++i) {
            KT[d0 + i][row]  = (float)kv[i];
            Vs[row][d0 + i]  = (float)vv[i];
            qsh[row][d0 + i] = (float)qv[i];
        }
    }
    __syncthreads();

    const int wave = t >> 6, lane = t & 63;
    const int ql = lane >> 4, j = lane & 15;
    const int qi = wave * 4 + ql;

    float s = 0.f;
    #pragma unroll
    for (int d = 0; d < 64; ++d) s = fmaf(qsh[qi][d], KT[d][j], s);
    s *= 0.125f;

    float m = s;
    #pragma unroll
    for (int off = 8; off > 0; off >>= 1) m = fmaxf(m, __shfl_xor(m, off, 16));
    float e = __expf(s - m);
    float sum = e;
    #pragma unroll
    for (int off = 8; off > 0; off >>= 1) sum += __shfl_xor(sum, off, 16);
    wsh[qi][j] = e / sum;

    #pragma unroll
    for (int q2 = 0; q2 < 4; ++q2) {
        int qq = wave * 4 + q2;
        float o = 0.f;
        #pragma unroll
        for (int jj = 0; jj < 16; ++jj)
            o = fmaf(wsh[qq][jj], Vs[jj][lane], o);
        att[((size_t)(b * Ss + q0 + qq)) * Dd + h * 64 + lane] = (__bf16)o;
    }
}

// ---------------------------------------------------------------------------
// Dense attention phase 1: scores for 16 selected queries x 128-key chunk.
// ---------------------------------------------------------------------------
__global__ void __launch_bounds__(256) attn_dense_qk(
    const __bf16* __restrict__ q, const __bf16* __restrict__ k,
    const int* __restrict__ sel_idx, float* __restrict__ Sbuf,
    unsigned* __restrict__ macc)
{
    const int b  = blockIdx.z, h = blockIdx.y, j0 = blockIdx.x * 128;
    const int t  = threadIdx.x;

    __shared__ float Ks[128][65];
    __shared__ float Qs[16][65];

    #pragma unroll
    for (int l = 0; l < 4; ++l) {
        int c = t + 256 * l;
        int row = c >> 3, seg = c & 7;
        bf16x8 kv = *(const bf16x8*)(k + ((size_t)(b * Ss + j0 + row)) * Dd + h * 64 + seg * 8);
        #pragma unroll
        for (int e = 0; e < 8; ++e) Ks[row][seg * 8 + e] = (float)kv[e];
    }
    if (t < 128) {
        int row = t >> 3, seg = t & 7;
        int i = sel_idx[b * Kk + row];
        bf16x8 qv = *(const bf16x8*)(q + ((size_t)(b * Ss + i)) * Dd + h * 64 + seg * 8);
        #pragma unroll
        for (int e = 0; e < 8; ++e) Qs[row][seg * 8 + e] = (float)qv[e];
    }
    __syncthreads();

    const int qi = t >> 4, ks = t & 15;
    const int bhq = (b * Hh + h) * Kk + qi;
    float lmax = -1e30f;
    #pragma unroll
    for (int s8 = 0; s8 < 8; ++s8) {
        int j = ks + s8 * 16;
        float s = 0.f;
        #pragma unroll
        for (int d = 0; d < 64; ++d) s = fmaf(Qs[qi][d], Ks[j][d], s);
        s *= 0.125f;
        Sbuf[(size_t)bhq * Ss + j0 + j] = s;
        lmax = fmaxf(lmax, s);
    }
    #pragma unroll
    for (int off = 8; off > 0; off >>= 1) lmax = fmaxf(lmax, __shfl_xor(lmax, off, 16));
    if (ks == 0) atomicMax(macc + bhq, fmap(lmax));
}

// ---------------------------------------------------------------------------
// Dense attention phase 2: e = exp(s - m); partial sums + partial PV atomics.
// ---------------------------------------------------------------------------
__global__ void __launch_bounds__(256) attn_dense_pv(
    const __bf16* __restrict__ v, const float* __restrict__ Sbuf,
    const unsigned* __restrict__ macc, float* __restrict__ lsum,
    float* __restrict__ oacc)
{
    const int b  = blockIdx.z, h = blockIdx.y, j0 = blockIdx.x * 128;
    const int t  = threadIdx.x;

    __shared__ float Vs[128][64];
    __shared__ float Es[16][144];

    #pragma unroll
    for (int l = 0; l < 4; ++l) {
        int c = t + 256 * l;
        int row = c >> 3, seg = c & 7;
        bf16x8 vv = *(const bf16x8*)(v + ((size_t)(b * Ss + j0 + row)) * Dd + h * 64 + seg * 8);
        #pragma unroll
        for (int e = 0; e < 8; ++e) Vs[row][seg * 8 + e] = (float)vv[e];
    }

    const int qi = t >> 4, ks = t & 15;
    const int bhq = (b * Hh + h) * Kk + qi;
    const float mq = funmap(macc[bhq]);
    float psum = 0.f;
    #pragma unroll
    for (int s8 = 0; s8 < 8; ++s8) {
        int j = ks + s8 * 16;
        float e = __expf(Sbuf[(size_t)bhq * Ss + j0 + j] - mq);
        Es[qi][j] = e;
        psum += e;
    }
    #pragma unroll
    for (int off = 8; off > 0; off >>= 1) psum += __shfl_xor(psum, off, 16);
    if (ks == 0) atomicAdd(lsum + bhq, psum);
    __syncthreads();

    const int d = t & 63, qg = t >> 6;
    #pragma unroll
    for (int qq = 0; qq < 4; ++qq) {
        int qx = qg * 4 + qq;
        float o = 0.f;
        #pragma unroll 4
        for (int jj = 0; jj < 128; ++jj)
            o = fmaf(Es[qx][jj], Vs[jj][d], o);
        atomicAdd(oacc + (size_t)((b * Hh + h) * Kk + qx) * 64 + d, o);
    }
}

// ---------------------------------------------------------------------------
// Dense attention phase 3: att[selected rows] = oacc / lsum.
// ---------------------------------------------------------------------------
__global__ void __launch_bounds__(64) attn_dense_fin(
    const float* __restrict__ oacc, const float* __restrict__ lsum,
    const int* __restrict__ sel_idx, __bf16* __restrict__ att)
{
    int bid = blockIdx.x;
    int qi = bid & 15, h = (bid >> 4) & 15, b = bid >> 8;
    int bhq = (b * Hh + h) * Kk + qi;
    int i = sel_idx[b * Kk + qi];
    float val = oacc[(size_t)bhq * 64 + threadIdx.x] / lsum[bhq];
    att[((size_t)(b * Ss + i)) * Dd + h * 64 + threadIdx.x] = (__bf16)val;
}

// ---------------------------------------------------------------------------
extern "C" void kernel_launch(void* const* d_in, const int* in_sizes, int n_in,
                              void* d_out, int out_size, void* d_ws, size_t ws_size,
                              hipStream_t stream)
{
    const float* x   = (const float*)d_in[0];
    const float* Wq  = (const float*)d_in[1];
    const float* bq  = (const float*)d_in[2];
    const float* Wk  = (const float*)d_in[3];
    const float* bk  = (const float*)d_in[4];
    const float* Wv  = (const float*)d_in[5];
    const float* bv  = (const float*)d_in[6];
    const float* Wo  = (const float*)d_in[7];
    const float* bo  = (const float*)d_in[8];
    const float* Ws1 = (const float*)d_in[9];
    const float* bs1 = (const float*)d_in[10];
    const float* Ws2 = (const float*)d_in[11];
    float* out = (float*)d_out;

    const size_t MSD = (size_t)Bb * Ss * Dd;   // 4,194,304
    const int M = Bb * Ss;                     // 4096

    char* p = (char*)d_ws;
    __bf16* qb  = (__bf16*)p; p += MSD * sizeof(__bf16);
    __bf16* kb  = (__bf16*)p; p += MSD * sizeof(__bf16);
    __bf16* vb  = (__bf16*)p; p += MSD * sizeof(__bf16);
    __bf16* att = (__bf16*)p; p += MSD * sizeof(__bf16);
    __bf16* xb  = (__bf16*)p; p += MSD * sizeof(__bf16);
    __bf16* xlo = (__bf16*)p; p += MSD * sizeof(__bf16);
    __bf16* WqT = (__bf16*)p; p += (size_t)Dd * Dd * sizeof(__bf16);
    __bf16* WkT = (__bf16*)p; p += (size_t)Dd * Dd * sizeof(__bf16);
    __bf16* WvT = (__bf16*)p; p += (size_t)Dd * Dd * sizeof(__bf16);
    __bf16* WoT = (__bf16*)p; p += (size_t)Dd * Dd * sizeof(__bf16);
    __bf16* W1Th = (__bf16*)p; p += (size_t)512 * Dd * sizeof(__bf16);
    __bf16* W1Tl = (__bf16*)p; p += (size_t)512 * Dd * sizeof(__bf16);
    float* imp  = (float*)p; p += (size_t)Bb * Ss * sizeof(float);
    int* sel_idx = (int*)p; p += (size_t)Bb * Kk * sizeof(int);
    float* oacc = (float*)p; p += (size_t)Bb * Hh * Kk * 64 * sizeof(float);
    float* lsum = (float*)p; p += (size_t)Bb * Hh * Kk * sizeof(float);
    unsigned* macc = (unsigned*)p; p += (size_t)Bb * Hh * Kk * sizeof(unsigned);
    float* Sbuf = (float*)xlo;   // alias: xlo dead after gemm_qkv_ind

    // 1) Merged prep: pack x -> bf16 hi/lo + zero accumulators (blocks
    //    0..4095) and weight transposes (blocks 4096..9215).
    prep_kernel<<<dim3(4096 + 5120), 256, 0, stream>>>(
        x, xb, xlo, imp, oacc, lsum, macc,
        Wq, Wk, Wv, Wo, WqT, WkT, WvT, WoT, Ws1, W1Th, W1Tl);
    // 2) FUSED: QKV projections (z<3, BK=64) + hi/lo indexer (z==3), 1D grid
    //    with z interleaved for co-scheduling.
    gemm_qkv_ind<<<dim3(1024), 256, 0, stream>>>(
        xb, xlo, WqT, WkT, WvT, bq, bk, bv, qb, kb, vb,
        W1Th, W1Tl, bs1, Ws2, imp);
    // 3) Exact top-K selection.
    topk_kernel<<<dim3(Bb), 256, 0, stream>>>(imp, sel_idx);
    // 4) Attention: sparse writes all rows; dense 3-phase overwrites the 16
    //    selected rows.
    attn_sparse<<<dim3(Ss / 16, Hh, Bb), 256, 0, stream>>>(qb, kb, vb, sel_idx, att);
    attn_dense_qk<<<dim3(Ss / 128, Hh, Bb), 256, 0, stream>>>(qb, kb, sel_idx, Sbuf, macc);
    attn_dense_pv<<<dim3(Ss / 128, Hh, Bb), 256, 0, stream>>>(vb, Sbuf, macc, lsum, oacc);
    attn_dense_fin<<<dim3(Bb * Hh * Kk), 64, 0, stream>>>(oacc, lsum, sel_idx, att);
    // 5) Output projection: 64x128 tile, BK=64, 512 blocks.
    gemm_out<<<dim3(8, 64), 256, 0, stream>>>(att, WoT, bo, out, M, Dd, Dd);
}